// Round 1
// baseline (2215.312 us; speedup 1.0000x reference)
//
#include <hip/hip_runtime.h>
#include <stdint.h>

// ---------------------------------------------------------------------------
// SparseDiffAttention: dense flash attn (+diff colsum) -> per-group top-k
// column select (+JAX threefry ~1% random cols) -> sparse flash attn ->
// out = stack([o, o - spo]).  All fp32 (cs threshold selection needs fp32).
// ---------------------------------------------------------------------------

#define JAX_PARTITIONABLE 1   // modern JAX default; flip to 0 if mask mismatch

namespace {
constexpr int H   = 16;
constexpr int N   = 3072;
constexpr int Dh  = 128;
constexpr int M   = 16;            // query groups per head (N / 192)
constexpr int BQ  = 64;            // query rows per workgroup
constexpr int TK  = 64;            // key tile
constexpr int NQB = N / BQ;        // 48 query blocks per head
constexpr int NT  = N / TK;        // 48 key tiles
constexpr float SCALE = 0.08838834764831845f;  // 1/sqrt(128)
constexpr size_t HEAD_STRIDE = (size_t)N * Dh;
constexpr size_t OUT_HALF    = (size_t)H * N * Dh;   // 6,291,456

constexpr int PT_LD = BQ + 4;      // 68: padded row-stride of P~^T tile

// dynamic LDS sizes (floats)
constexpr int DENSE_SM  = 3*BQ*Dh + TK*PT_LD + 16*64 + 16*64 + 16*68 + 5*64; // 32384
constexpr int SPARSE_SM = 3*BQ*Dh + TK*PT_LD + 16*64 + 16*64 + 3*64 + 64;    // 31232

// ws layout (float units)
constexpr size_t CSPART_OFF = 0;                          // [H][NQB][N] f32
constexpr size_t CSPART_SZ  = (size_t)H * NQB * N;
constexpr size_t IDX_OFF    = CSPART_OFF + CSPART_SZ;     // [H][M][N] i32
constexpr size_t IDX_SZ     = (size_t)H * M * N;
constexpr size_t NSEL_OFF   = IDX_OFF + IDX_SZ;           // [H*M] i32
}

// ------------------------------ threefry -----------------------------------
__device__ __forceinline__ void tf_round(uint32_t& x0, uint32_t& x1, int r) {
  x0 += x1; x1 = (x1 << r) | (x1 >> (32 - r)); x1 ^= x0;
}
__device__ __forceinline__ void tf2x32(uint32_t k0, uint32_t k1,
                                       uint32_t x0, uint32_t x1,
                                       uint32_t& y0, uint32_t& y1) {
  uint32_t k2 = k0 ^ k1 ^ 0x1BD11BDAu;
  x0 += k0; x1 += k1;
  tf_round(x0,x1,13); tf_round(x0,x1,15); tf_round(x0,x1,26); tf_round(x0,x1,6);
  x0 += k1; x1 += k2 + 1u;
  tf_round(x0,x1,17); tf_round(x0,x1,29); tf_round(x0,x1,16); tf_round(x0,x1,24);
  x0 += k2; x1 += k0 + 2u;
  tf_round(x0,x1,13); tf_round(x0,x1,15); tf_round(x0,x1,26); tf_round(x0,x1,6);
  x0 += k0; x1 += k1 + 3u;
  tf_round(x0,x1,17); tf_round(x0,x1,29); tf_round(x0,x1,16); tf_round(x0,x1,24);
  x0 += k1; x1 += k2 + 4u;
  tf_round(x0,x1,13); tf_round(x0,x1,15); tf_round(x0,x1,26); tf_round(x0,x1,6);
  x0 += k2; x1 += k0 + 5u;
  y0 = x0; y1 = x1;
}

// jax.random.randint(key(42), (1,16,16,3072), 0, 100) == 0  for flat idx
__device__ __forceinline__ bool jax_rand_zero(uint32_t idx) {
  uint32_t hi, lo, r0, r1;
#if JAX_PARTITIONABLE
  uint32_t a0,a1,b0,b1;
  tf2x32(0u,42u, 0u,0u, a0,a1);        // split (foldlike): key0 = tf(key,(0,0))
  tf2x32(0u,42u, 0u,1u, b0,b1);        //                   key1 = tf(key,(0,1))
  tf2x32(a0,a1, 0u, idx, r0,r1);  hi = r0 ^ r1;
  tf2x32(b0,b1, 0u, idx, r0,r1);  lo = r0 ^ r1;
#else
  uint32_t p0x,p0y,p1x,p1y;
  tf2x32(0u,42u, 0u,2u, p0x,p0y);      // original split: counts [0,1,2,3]
  tf2x32(0u,42u, 1u,3u, p1x,p1y);      // key0=(x0(0,2),x0(1,3)) key1=(x1(0,2),x1(1,3))
  const uint32_t half = (uint32_t)((size_t)H*M*N) / 2u;  // 393216
  uint32_t i = (idx < half) ? idx : (idx - half);
  uint32_t h0,h1,l0,l1;
  tf2x32(p0x, p1x, i, i + half, h0, h1);
  tf2x32(p0y, p1y, i, i + half, l0, l1);
  hi = (idx < half) ? h0 : h1;
  lo = (idx < half) ? l0 : l1;
#endif
  // span=100; multiplier = (2^16 % 100)^2 % 100 = 96
  uint32_t off = ((hi % 100u) * 96u + (lo % 100u)) % 100u;
  return off == 0u;
}

// --------------------------- dense flash + colsum ---------------------------
__global__ __launch_bounds__(256, 1) void dense_attn_kernel(
    const float* __restrict__ Qm, const float* __restrict__ Km,
    const float* __restrict__ Vm, const float* __restrict__ PL,
    float* __restrict__ Out, float* __restrict__ csPart)
{
  extern __shared__ float sm[];
  float* qs   = sm;                    // [64][128] swizzled
  float* ks   = qs + BQ*Dh;            // [64][128] swizzled
  float* vs   = ks + TK*Dh;            // [64][128] linear
  float* pT   = vs + TK*Dh;            // [TK][PT_LD]  P~ transposed (col-major)
  float* redA = pT + TK*PT_LD;         // [16][64] rowmax
  float* redB = redA + 16*64;          // [16][64] rowsum
  float* redC = redB + 16*64;          // [16][68] colsum
  float* mrow = redC + 16*68;          // [64]
  float* lrow = mrow + 64;
  float* srow = lrow + 64;
  float* wrow = srow + 64;
  float* plr  = wrow + 64;

  const int qb  = blockIdx.x;
  const int h   = blockIdx.y;
  const int q0  = qb * BQ;
  const int tid = threadIdx.x;
  const int tq  = tid & 15;            // s-phase: rows 4tq..4tq+3 | pv: same rows
  const int tk4 = tid >> 4;            // s-phase: cols 4tk4..+3   | pv: dims 8*tk4..+7
  const int swq = tq & 7;              // (row>>2)&7 for rows 4tq+i
  const int swk = tk4 & 7;

  // stage Q (prescaled, XOR-swizzled source so LDS stays linear)
  const float* qg = Qm + (size_t)h * HEAD_STRIDE + (size_t)q0 * Dh;
  #pragma unroll
  for (int it = 0; it < 8; ++it) {
    int f = tid + 256*it;
    int row = f >> 5, d4 = f & 31;
    int e4 = d4 ^ ((row >> 2) & 7);
    float4 val = *(const float4*)(qg + row*Dh + (e4 << 2));
    val.x *= SCALE; val.y *= SCALE; val.z *= SCALE; val.w *= SCALE;
    *(float4*)(qs + row*Dh + (d4 << 2)) = val;
  }
  if (tid < 64) {
    mrow[tid] = -1e30f;
    lrow[tid] = 0.0f;
    plr[tid]  = PL[(size_t)h * N + q0 + tid];
  }

  float oacc[4][8];
  #pragma unroll
  for (int i = 0; i < 4; ++i)
    #pragma unroll
    for (int j = 0; j < 8; ++j) oacc[i][j] = 0.0f;

  for (int kt = 0; kt < NT; ++kt) {
    __syncthreads();                                    // prev PV done
    const float* kg = Km + (size_t)h * HEAD_STRIDE + (size_t)(kt*TK) * Dh;
    const float* vg = Vm + (size_t)h * HEAD_STRIDE + (size_t)(kt*TK) * Dh;
    #pragma unroll
    for (int it = 0; it < 8; ++it) {
      int f = tid + 256*it;
      int row = f >> 5, d4 = f & 31;
      int e4 = d4 ^ ((row >> 2) & 7);
      *(float4*)(ks + row*Dh + (d4 << 2)) = *(const float4*)(kg + row*Dh + (e4 << 2));
      *(float4*)(vs + row*Dh + (d4 << 2)) = *(const float4*)(vg + row*Dh + (d4 << 2));
    }
    __syncthreads();

    // s = q.k  (scale folded into qs)
    float acc[4][4];
    #pragma unroll
    for (int i = 0; i < 4; ++i)
      #pragma unroll
      for (int j = 0; j < 4; ++j) acc[i][j] = 0.0f;
    for (int d4 = 0; d4 < 32; ++d4) {
      const int qo = ((d4 ^ swq) << 2);
      const int ko = ((d4 ^ swk) << 2);
      float4 qv[4], kv[4];
      #pragma unroll
      for (int i = 0; i < 4; ++i) qv[i] = *(const float4*)(qs + (4*tq + i)*Dh + qo);
      #pragma unroll
      for (int j = 0; j < 4; ++j) kv[j] = *(const float4*)(ks + (4*tk4 + j)*Dh + ko);
      #pragma unroll
      for (int i = 0; i < 4; ++i)
        #pragma unroll
        for (int j = 0; j < 4; ++j)
          acc[i][j] += qv[i].x*kv[j].x + qv[i].y*kv[j].y + qv[i].z*kv[j].z + qv[i].w*kv[j].w;
    }

    // tile row-max
    #pragma unroll
    for (int i = 0; i < 4; ++i) {
      float rm = fmaxf(fmaxf(acc[i][0], acc[i][1]), fmaxf(acc[i][2], acc[i][3]));
      redA[tk4*64 + 4*tq + i] = rm;
    }
    __syncthreads();
    if (tid < 64) {
      float m0 = redA[tid];
      #pragma unroll
      for (int t = 1; t < 16; ++t) m0 = fmaxf(m0, redA[t*64 + tid]);
      float mo = mrow[tid];
      float mn = fmaxf(mo, m0);
      srow[tid] = __expf(mo - mn);
      mrow[tid] = mn;
      wrow[tid] = __expf(mn - plr[tid]);   // colsum weight exp(m - prev_l)
    }
    __syncthreads();

    // P~ = exp(s - m); row sums; colsum partial
    float mni[4], wi[4];
    #pragma unroll
    for (int i = 0; i < 4; ++i) { mni[i] = mrow[4*tq + i]; wi[i] = wrow[4*tq + i]; }
    float rs[4] = {0.f,0.f,0.f,0.f};
    float cl[4] = {0.f,0.f,0.f,0.f};
    float pv_[4][4];
    #pragma unroll
    for (int i = 0; i < 4; ++i)
      #pragma unroll
      for (int j = 0; j < 4; ++j) {
        float p = __expf(acc[i][j] - mni[i]);
        pv_[i][j] = p; rs[i] += p; cl[j] += p * wi[i];
      }
    #pragma unroll
    for (int j = 0; j < 4; ++j) {
      float4 pj; pj.x = pv_[0][j]; pj.y = pv_[1][j]; pj.z = pv_[2][j]; pj.w = pv_[3][j];
      *(float4*)(pT + (4*tk4 + j)*PT_LD + 4*tq) = pj;
    }
    #pragma unroll
    for (int i = 0; i < 4; ++i) redB[tk4*64 + 4*tq + i] = rs[i];
    #pragma unroll
    for (int j = 0; j < 4; ++j) redC[tq*68 + 4*tk4 + j] = cl[j];
    __syncthreads();
    if (tid < 64) {
      float s0 = redB[tid];
      #pragma unroll
      for (int t = 1; t < 16; ++t) s0 += redB[t*64 + tid];
      lrow[tid] = lrow[tid]*srow[tid] + s0;
      float c0 = redC[tid];
      #pragma unroll
      for (int t = 1; t < 16; ++t) c0 += redC[t*68 + tid];
      csPart[((size_t)h*NQB + qb)*N + kt*TK + tid] = c0;
    }

    // PV (after the barrier above pT/vs are ready; srow stable)
    float sc[4];
    #pragma unroll
    for (int i = 0; i < 4; ++i) sc[i] = srow[4*tq + i];
    #pragma unroll
    for (int i = 0; i < 4; ++i)
      #pragma unroll
      for (int j = 0; j < 8; ++j) oacc[i][j] *= sc[i];
    for (int kk = 0; kk < TK; ++kk) {
      float4 p4 = *(const float4*)(pT + kk*PT_LD + 4*tq);
      float4 va = *(const float4*)(vs + kk*Dh + (tk4 << 3));
      float4 vb = *(const float4*)(vs + kk*Dh + (tk4 << 3) + 4);
      float p_[4]; p_[0]=p4.x; p_[1]=p4.y; p_[2]=p4.z; p_[3]=p4.w;
      float v_[8]; v_[0]=va.x; v_[1]=va.y; v_[2]=va.z; v_[3]=va.w;
                   v_[4]=vb.x; v_[5]=vb.y; v_[6]=vb.z; v_[7]=vb.w;
      #pragma unroll
      for (int i = 0; i < 4; ++i)
        #pragma unroll
        for (int j = 0; j < 8; ++j) oacc[i][j] += p_[i] * v_[j];
    }
  }

  __syncthreads();
  #pragma unroll
  for (int i = 0; i < 4; ++i) {
    float inv = 1.0f / lrow[4*tq + i];
    size_t off = (size_t)h * HEAD_STRIDE + (size_t)(q0 + 4*tq + i) * Dh + (tk4 << 3);
    float4 a, b;
    a.x = oacc[i][0]*inv; a.y = oacc[i][1]*inv; a.z = oacc[i][2]*inv; a.w = oacc[i][3]*inv;
    b.x = oacc[i][4]*inv; b.y = oacc[i][5]*inv; b.z = oacc[i][6]*inv; b.w = oacc[i][7]*inv;
    *(float4*)(Out + off)     = a;
    *(float4*)(Out + off + 4) = b;
  }
}

// ------------------- selection: radix top-k + random mask -------------------
__global__ __launch_bounds__(256) void select_kernel(
    const float* __restrict__ csPart, const int* __restrict__ topkPtr,
    int* __restrict__ idxList, int* __restrict__ nSel)
{
  __shared__ uint32_t ubits[N];
  __shared__ int hist[256];
  __shared__ int cnt1[256], base1[256];
  __shared__ int sh_digit, sh_kk, sh_total;

  const int bh = blockIdx.x;           // h*16+g
  const int h = bh >> 4, g = bh & 15;
  const int tid = threadIdx.x;

  const float* p0 = csPart + ((size_t)h*NQB + 3*g) * N;
  for (int c = tid; c < N; c += 256) {
    float v = p0[c] + p0[N + c] + p0[2*(size_t)N + c];   // fixed-order reduce
    ubits[c] = __float_as_uint(v);                        // v>0 -> monotonic bits
  }
  __syncthreads();

  const int K = topkPtr[0];
  uint32_t prefix = 0; int kk = K;
  for (int pass = 0; pass < 4; ++pass) {
    const int shift = 24 - 8*pass;
    const uint32_t hm = (pass == 0) ? 0u : (0xFFFFFFFFu << (shift + 8));
    hist[tid] = 0;
    __syncthreads();
    for (int c = tid; c < N; c += 256) {
      uint32_t b = ubits[c];
      if ((b & hm) == (prefix & hm)) atomicAdd(&hist[(b >> shift) & 255], 1);
    }
    __syncthreads();
    if (tid == 0) {
      int cum = 0, d = 255;
      for (; d > 0; --d) { int hc = hist[d]; if (cum + hc >= kk) break; cum += hc; }
      sh_digit = d; sh_kk = kk - cum;
    }
    __syncthreads();
    prefix |= ((uint32_t)sh_digit) << shift;
    kk = sh_kk;
    __syncthreads();
  }
  const uint32_t tbits = prefix;       // value of k-th largest; kk = #ties to keep

  // rank ties (ascending index), chunked scan
  const int CH = N / 256;              // 12
  const int c0 = tid * CH;
  int eqc = 0;
  for (int j = 0; j < CH; ++j) eqc += (ubits[c0 + j] == tbits) ? 1 : 0;
  cnt1[tid] = eqc;
  __syncthreads();
  if (tid == 0) { int run = 0; for (int t = 0; t < 256; ++t) { base1[t] = run; run += cnt1[t]; } }
  __syncthreads();
  int er = base1[tid];
  __syncthreads();

  bool fl[12]; int selc = 0;
  for (int j = 0; j < CH; ++j) {
    uint32_t b = ubits[c0 + j];
    bool s = (b > tbits);
    if (b == tbits) { if (er < kk) s = true; ++er; }
    if (!s) s = jax_rand_zero((uint32_t)bh * (uint32_t)N + (uint32_t)(c0 + j));
    fl[j] = s; selc += s ? 1 : 0;
  }
  cnt1[tid] = selc;
  __syncthreads();
  if (tid == 0) { int run = 0; for (int t = 0; t < 256; ++t) { base1[t] = run; run += cnt1[t]; } sh_total = run; }
  __syncthreads();
  int w = base1[tid];
  int* il = idxList + (size_t)bh * N;
  for (int j = 0; j < CH; ++j) if (fl[j]) il[w++] = c0 + j;
  if (tid == 0) nSel[bh] = sh_total;
}

// ----------------------- sparse flash + out_cache ---------------------------
__global__ __launch_bounds__(256, 1) void sparse_attn_kernel(
    const float* __restrict__ Qm, const float* __restrict__ Km,
    const float* __restrict__ Vm, const int* __restrict__ idxList,
    const int* __restrict__ nSel, float* __restrict__ Out)
{
  extern __shared__ float sm[];
  float* qs   = sm;
  float* ks   = qs + BQ*Dh;
  float* vs   = ks + TK*Dh;
  float* pT   = vs + TK*Dh;
  float* redA = pT + TK*PT_LD;
  float* redB = redA + 16*64;
  float* mrow = redB + 16*64;
  float* lrow = mrow + 64;
  float* srow = lrow + 64;
  int*   idxs = (int*)(srow + 64);

  const int qb  = blockIdx.x;
  const int h   = blockIdx.y;
  const int g   = qb / 3;
  const int q0  = qb * BQ;
  const int tid = threadIdx.x;
  const int tq  = tid & 15;
  const int tk4 = tid >> 4;
  const int swq = tq & 7;
  const int swk = tk4 & 7;

  int nsel = nSel[h*M + g];
  if (nsel > N) nsel = N;
  const int* il = idxList + ((size_t)h*M + g) * N;

  const float* qg = Qm + (size_t)h * HEAD_STRIDE + (size_t)q0 * Dh;
  #pragma unroll
  for (int it = 0; it < 8; ++it) {
    int f = tid + 256*it;
    int row = f >> 5, d4 = f & 31;
    int e4 = d4 ^ ((row >> 2) & 7);
    float4 val = *(const float4*)(qg + row*Dh + (e4 << 2));
    val.x *= SCALE; val.y *= SCALE; val.z *= SCALE; val.w *= SCALE;
    *(float4*)(qs + row*Dh + (d4 << 2)) = val;
  }
  if (tid < 64) { mrow[tid] = -1e30f; lrow[tid] = 0.0f; }

  float oacc[4][8];
  #pragma unroll
  for (int i = 0; i < 4; ++i)
    #pragma unroll
    for (int j = 0; j < 8; ++j) oacc[i][j] = 0.0f;

  const int nt = (nsel + TK - 1) / TK;
  const float* kb = Km + (size_t)h * HEAD_STRIDE;
  const float* vb = Vm + (size_t)h * HEAD_STRIDE;

  for (int t = 0; t < nt; ++t) {
    const int cnt = min(TK, nsel - t*TK);
    __syncthreads();
    if (tid < 64) idxs[tid] = (tid < cnt) ? il[t*TK + tid] : 0;
    __syncthreads();
    #pragma unroll
    for (int it = 0; it < 8; ++it) {
      int f = tid + 256*it;
      int row = f >> 5, d4 = f & 31;
      int e4 = d4 ^ ((row >> 2) & 7);
      int c  = idxs[row];
      *(float4*)(ks + row*Dh + (d4 << 2)) = *(const float4*)(kb + (size_t)c*Dh + (e4 << 2));
      *(float4*)(vs + row*Dh + (d4 << 2)) = *(const float4*)(vb + (size_t)c*Dh + (d4 << 2));
    }
    __syncthreads();

    float acc[4][4];
    #pragma unroll
    for (int i = 0; i < 4; ++i)
      #pragma unroll
      for (int j = 0; j < 4; ++j) acc[i][j] = 0.0f;
    for (int d4 = 0; d4 < 32; ++d4) {
      const int qo = ((d4 ^ swq) << 2);
      const int ko = ((d4 ^ swk) << 2);
      float4 qv[4], kv[4];
      #pragma unroll
      for (int i = 0; i < 4; ++i) qv[i] = *(const float4*)(qs + (4*tq + i)*Dh + qo);
      #pragma unroll
      for (int j = 0; j < 4; ++j) kv[j] = *(const float4*)(ks + (4*tk4 + j)*Dh + ko);
      #pragma unroll
      for (int i = 0; i < 4; ++i)
        #pragma unroll
        for (int j = 0; j < 4; ++j)
          acc[i][j] += qv[i].x*kv[j].x + qv[i].y*kv[j].y + qv[i].z*kv[j].z + qv[i].w*kv[j].w;
    }
    #pragma unroll
    for (int j = 0; j < 4; ++j)
      if (4*tk4 + j >= cnt) { acc[0][j] = acc[1][j] = acc[2][j] = acc[3][j] = -1e30f; }

    #pragma unroll
    for (int i = 0; i < 4; ++i) {
      float rm = fmaxf(fmaxf(acc[i][0], acc[i][1]), fmaxf(acc[i][2], acc[i][3]));
      redA[tk4*64 + 4*tq + i] = rm;
    }
    __syncthreads();
    if (tid < 64) {
      float m0 = redA[tid];
      #pragma unroll
      for (int tt = 1; tt < 16; ++tt) m0 = fmaxf(m0, redA[tt*64 + tid]);
      float mo = mrow[tid];
      float mn = fmaxf(mo, m0);
      srow[tid] = __expf(mo - mn);
      mrow[tid] = mn;
    }
    __syncthreads();

    float mni[4];
    #pragma unroll
    for (int i = 0; i < 4; ++i) mni[i] = mrow[4*tq + i];
    float rs[4] = {0.f,0.f,0.f,0.f};
    float pv_[4][4];
    #pragma unroll
    for (int i = 0; i < 4; ++i)
      #pragma unroll
      for (int j = 0; j < 4; ++j) {
        float p = __expf(acc[i][j] - mni[i]);
        pv_[i][j] = p; rs[i] += p;
      }
    #pragma unroll
    for (int j = 0; j < 4; ++j) {
      float4 pj; pj.x = pv_[0][j]; pj.y = pv_[1][j]; pj.z = pv_[2][j]; pj.w = pv_[3][j];
      *(float4*)(pT + (4*tk4 + j)*PT_LD + 4*tq) = pj;
    }
    #pragma unroll
    for (int i = 0; i < 4; ++i) redB[tk4*64 + 4*tq + i] = rs[i];
    __syncthreads();
    if (tid < 64) {
      float s0 = redB[tid];
      #pragma unroll
      for (int tt = 1; tt < 16; ++tt) s0 += redB[tt*64 + tid];
      lrow[tid] = lrow[tid]*srow[tid] + s0;
    }

    float sc[4];
    #pragma unroll
    for (int i = 0; i < 4; ++i) sc[i] = srow[4*tq + i];
    #pragma unroll
    for (int i = 0; i < 4; ++i)
      #pragma unroll
      for (int j = 0; j < 8; ++j) oacc[i][j] *= sc[i];
    for (int kk = 0; kk < TK; ++kk) {
      float4 p4 = *(const float4*)(pT + kk*PT_LD + 4*tq);
      float4 va = *(const float4*)(vs + kk*Dh + (tk4 << 3));
      float4 vbv = *(const float4*)(vs + kk*Dh + (tk4 << 3) + 4);
      float p_[4]; p_[0]=p4.x; p_[1]=p4.y; p_[2]=p4.z; p_[3]=p4.w;
      float v_[8]; v_[0]=va.x; v_[1]=va.y; v_[2]=va.z; v_[3]=va.w;
                   v_[4]=vbv.x; v_[5]=vbv.y; v_[6]=vbv.z; v_[7]=vbv.w;
      #pragma unroll
      for (int i = 0; i < 4; ++i)
        #pragma unroll
        for (int j = 0; j < 8; ++j) oacc[i][j] += p_[i] * v_[j];
    }
  }

  __syncthreads();
  #pragma unroll
  for (int i = 0; i < 4; ++i) {
    float inv = 1.0f / lrow[4*tq + i];
    size_t off = (size_t)h * HEAD_STRIDE + (size_t)(q0 + 4*tq + i) * Dh + (tk4 << 3);
    float4 oa = *(const float4*)(Out + off);
    float4 ob = *(const float4*)(Out + off + 4);
    float4 ca, cb;
    ca.x = oa.x - oacc[i][0]*inv; ca.y = oa.y - oacc[i][1]*inv;
    ca.z = oa.z - oacc[i][2]*inv; ca.w = oa.w - oacc[i][3]*inv;
    cb.x = ob.x - oacc[i][4]*inv; cb.y = ob.y - oacc[i][5]*inv;
    cb.z = ob.z - oacc[i][6]*inv; cb.w = ob.w - oacc[i][7]*inv;
    *(float4*)(Out + OUT_HALF + off)     = ca;
    *(float4*)(Out + OUT_HALF + off + 4) = cb;
  }
}

// ------------------------------- launch -------------------------------------
extern "C" void kernel_launch(void* const* d_in, const int* in_sizes, int n_in,
                              void* d_out, int out_size, void* d_ws, size_t ws_size,
                              hipStream_t stream) {
  const float* q  = (const float*)d_in[0];
  const float* k  = (const float*)d_in[1];
  const float* v  = (const float*)d_in[2];
  const float* pl = (const float*)d_in[3];
  const int* topk = (const int*)d_in[4];
  float* out = (float*)d_out;
  float* ws  = (float*)d_ws;

  float* csPart = ws + CSPART_OFF;
  int*   idxL   = (int*)(ws + IDX_OFF);
  int*   nSel   = (int*)(ws + NSEL_OFF);

  (void)hipFuncSetAttribute((const void*)dense_attn_kernel,
      hipFuncAttributeMaxDynamicSharedMemorySize, DENSE_SM * 4);
  (void)hipFuncSetAttribute((const void*)sparse_attn_kernel,
      hipFuncAttributeMaxDynamicSharedMemorySize, SPARSE_SM * 4);

  dense_attn_kernel<<<dim3(NQB, H), 256, DENSE_SM * 4, stream>>>(q, k, v, pl, out, csPart);
  select_kernel<<<dim3(H * M), 256, 0, stream>>>(csPart, topk, idxL, nSel);
  sparse_attn_kernel<<<dim3(NQB, H), 256, SPARSE_SM * 4, stream>>>(q, k, v, idxL, nSel, out);
}

// Round 4
// 890.932 us; speedup vs baseline: 2.4865x; 2.4865x over previous
//
#include <hip/hip_runtime.h>
#include <stdint.h>

// ---------------------------------------------------------------------------
// SparseDiffAttention R3: dense flash attn on MFMA (split-bf16 QK, bf16 PV via
// pre-transposed Vt) + coarse colsum -> select with exact fp32 recompute of
// near-threshold candidates (+threefry random cols) -> sparse fp32 flash
// -> out = stack([o, o - spo]).
// ---------------------------------------------------------------------------

#define JAX_PARTITIONABLE 1

namespace {
constexpr int H   = 16;
constexpr int N   = 3072;
constexpr int Dh  = 128;
constexpr int M   = 16;
constexpr int BQ  = 64;
constexpr int TK  = 64;
constexpr int NQB = N / BQ;        // 48
constexpr int NT  = N / TK;        // 48
constexpr float SCALE = 0.08838834764831845f;
constexpr size_t HEAD_STRIDE = (size_t)N * Dh;
constexpr size_t OUT_HALF    = (size_t)H * N * Dh;

constexpr int PT_LD = BQ + 4;
constexpr int IDXCAP = 1024;       // max selected columns per group
constexpr int CAND_MAX = 128;

// fallback fp32 dense / sparse kernel LDS (floats)
constexpr int DENSE_SM  = 3*BQ*Dh + TK*PT_LD + 16*64 + 16*64 + 16*68 + 5*64;
constexpr int SPARSE_SM = 3*BQ*Dh + TK*PT_LD + 16*64 + 16*64 + 3*64 + 64;

// MFMA dense kernel LDS layout (bytes)
constexpr int KH_OFF = 0;          // 64x128 bf16, row stride 256B, XOR swz
constexpr int KL_OFF = 16384;
constexpr int VT_OFF = 32768;      // 128(d) x 64(c) bf16, row 128B, XOR swz
constexpr int PB_OFF = 49152;      // 4 waves x 16q x 64c bf16, XOR swz
constexpr int CSR_OFF = 57344;     // 4 x 64 f32
constexpr int MFMA_SM = 58368;

// ws layout (bytes)
constexpr size_t CS_B   = 0;                        // [H][NQB][N] f32 = 9.44MB
constexpr size_t IDX_B  = 9437184;                  // [H][M][IDXCAP] i32 = 1MB
constexpr size_t NSEL_B = IDX_B + (size_t)H*M*IDXCAP*4;   // 10,485,760
constexpr size_t KH_B   = NSEL_B + 1024;            // [H][N][Dh] bf16
constexpr size_t KL_B   = KH_B + 12582912;
constexpr size_t NEED_B = KL_B + 12582912;          // 35,652,608
}

typedef float f4v __attribute__((ext_vector_type(4)));
typedef short s8v __attribute__((ext_vector_type(8)));

__device__ __forceinline__ unsigned short f2bf(float x) {
  unsigned u = __float_as_uint(x);
  unsigned r = u + 0x7FFFu + ((u >> 16) & 1u);
  return (unsigned short)(r >> 16);
}
__device__ __forceinline__ float bf2f(unsigned short b) {
  return __uint_as_float(((unsigned)b) << 16);
}

// ------------------------------ threefry -----------------------------------
__device__ __forceinline__ void tf_round(uint32_t& x0, uint32_t& x1, int r) {
  x0 += x1; x1 = (x1 << r) | (x1 >> (32 - r)); x1 ^= x0;
}
__device__ __forceinline__ void tf2x32(uint32_t k0, uint32_t k1,
                                       uint32_t x0, uint32_t x1,
                                       uint32_t& y0, uint32_t& y1) {
  uint32_t k2 = k0 ^ k1 ^ 0x1BD11BDAu;
  x0 += k0; x1 += k1;
  tf_round(x0,x1,13); tf_round(x0,x1,15); tf_round(x0,x1,26); tf_round(x0,x1,6);
  x0 += k1; x1 += k2 + 1u;
  tf_round(x0,x1,17); tf_round(x0,x1,29); tf_round(x0,x1,16); tf_round(x0,x1,24);
  x0 += k2; x1 += k0 + 2u;
  tf_round(x0,x1,13); tf_round(x0,x1,15); tf_round(x0,x1,26); tf_round(x0,x1,6);
  x0 += k0; x1 += k1 + 3u;
  tf_round(x0,x1,17); tf_round(x0,x1,29); tf_round(x0,x1,16); tf_round(x0,x1,24);
  x0 += k1; x1 += k2 + 4u;
  tf_round(x0,x1,13); tf_round(x0,x1,15); tf_round(x0,x1,26); tf_round(x0,x1,6);
  x0 += k2; x1 += k0 + 5u;
  y0 = x0; y1 = x1;
}

__device__ __forceinline__ bool jax_rand_zero(uint32_t idx) {
  uint32_t hi, lo, r0, r1;
#if JAX_PARTITIONABLE
  uint32_t a0,a1,b0,b1;
  tf2x32(0u,42u, 0u,0u, a0,a1);
  tf2x32(0u,42u, 0u,1u, b0,b1);
  tf2x32(a0,a1, 0u, idx, r0,r1);  hi = r0 ^ r1;
  tf2x32(b0,b1, 0u, idx, r0,r1);  lo = r0 ^ r1;
#else
  uint32_t p0x,p0y,p1x,p1y;
  tf2x32(0u,42u, 0u,2u, p0x,p0y);
  tf2x32(0u,42u, 1u,3u, p1x,p1y);
  const uint32_t half = (uint32_t)((size_t)H*M*N) / 2u;
  uint32_t i = (idx < half) ? idx : (idx - half);
  uint32_t h0,h1,l0,l1;
  tf2x32(p0x, p1x, i, i + half, h0, h1);
  tf2x32(p0y, p1y, i, i + half, l0, l1);
  hi = (idx < half) ? h0 : h1;
  lo = (idx < half) ? l0 : l1;
#endif
  uint32_t off = ((hi % 100u) * 96u + (lo % 100u)) % 100u;
  return off == 0u;
}

// ----------------------- precompute: K -> Kh,Kl bf16 ------------------------
__global__ __launch_bounds__(256) void split_bf16_kernel(
    const float* __restrict__ K, unsigned short* __restrict__ Kh,
    unsigned short* __restrict__ Kl)
{
  size_t i = ((size_t)blockIdx.x * 256 + threadIdx.x) * 4;
  float4 v = *(const float4*)(K + i);
  unsigned short h0 = f2bf(v.x), h1 = f2bf(v.y), h2 = f2bf(v.z), h3 = f2bf(v.w);
  unsigned short l0 = f2bf(v.x - bf2f(h0)), l1 = f2bf(v.y - bf2f(h1));
  unsigned short l2 = f2bf(v.z - bf2f(h2)), l3 = f2bf(v.w - bf2f(h3));
  uint2 hu, lu;
  hu.x = (unsigned)h0 | ((unsigned)h1 << 16); hu.y = (unsigned)h2 | ((unsigned)h3 << 16);
  lu.x = (unsigned)l0 | ((unsigned)l1 << 16); lu.y = (unsigned)l2 | ((unsigned)l3 << 16);
  *(uint2*)(Kh + i) = hu;
  *(uint2*)(Kl + i) = lu;
}

// ----------------------- precompute: V -> Vt bf16 [H][Dh][N] ----------------
__global__ __launch_bounds__(256) void transpose_v_kernel(
    const float* __restrict__ Vm, unsigned short* __restrict__ Vt)
{
  __shared__ unsigned short tb[64][132];
  const int h  = blockIdx.x;
  const int cb = blockIdx.y;          // 64-col tile
  const int tid = threadIdx.x;
  const float* vg = Vm + (size_t)h*HEAD_STRIDE + (size_t)(cb*64)*Dh;
  #pragma unroll
  for (int it = 0; it < 8; ++it) {
    int f = tid + 256*it;
    int c = f >> 5, d0 = (f & 31)*4;
    float4 v = *(const float4*)(vg + c*Dh + d0);
    tb[c][d0+0] = f2bf(v.x); tb[c][d0+1] = f2bf(v.y);
    tb[c][d0+2] = f2bf(v.z); tb[c][d0+3] = f2bf(v.w);
  }
  __syncthreads();
  unsigned short* vt = Vt + (size_t)h*((size_t)Dh*N) + (size_t)(cb*64);
  #pragma unroll
  for (int it = 0; it < 4; ++it) {
    int f = tid + 256*it;
    int d = f >> 3, sl = f & 7;       // 8 slots of 8 c's per d-row
    union { unsigned short us[8]; uint4 u; } o;
    #pragma unroll
    for (int i = 0; i < 8; ++i) o.us[i] = tb[sl*8 + i][d];
    *(uint4*)(vt + (size_t)d*N + sl*8) = o.u;
  }
}

// --------------------------- dense MFMA flash -------------------------------
__global__ __launch_bounds__(256, 2) void dense_mfma_kernel(
    const float* __restrict__ Qm, const unsigned short* __restrict__ Khg,
    const unsigned short* __restrict__ Klg, const unsigned short* __restrict__ Vtg,
    const float* __restrict__ PL, float* __restrict__ Out,
    float* __restrict__ csPart)
{
  extern __shared__ char smc[];
  char* KH = smc + KH_OFF;
  char* KL = smc + KL_OFF;
  char* VT = smc + VT_OFF;
  char* PB = smc + PB_OFF;
  float* CSR = (float*)(smc + CSR_OFF);

  // XCD-chunked swizzle: 768 blocks, 8 XCDs, 96 per chunk
  const int id  = blockIdx.x;
  const int wid = (id & 7) * 96 + (id >> 3);
  const int h   = wid / NQB;
  const int qb  = wid % NQB;
  const int q0  = qb * BQ;

  const int tid = threadIdx.x;
  const int wv  = tid >> 6;
  const int ln  = tid & 63;
  const int g   = ln >> 4;
  const int l15 = ln & 15;

  const size_t hqk = (size_t)h * HEAD_STRIDE;

  // ---- stage Q (scaled, split hi/lo) into KH/KL regions ----
  {
    const float* qg = Qm + hqk + (size_t)q0 * Dh;
    #pragma unroll
    for (int it = 0; it < 8; ++it) {
      int f = tid + 256*it;
      int row = f >> 5, d0 = (f & 31) * 4;
      float4 v = *(const float4*)(qg + row*Dh + d0);
      v.x *= SCALE; v.y *= SCALE; v.z *= SCALE; v.w *= SCALE;
      unsigned short h0 = f2bf(v.x), h1 = f2bf(v.y), h2 = f2bf(v.z), h3 = f2bf(v.w);
      unsigned short o0 = f2bf(v.x - bf2f(h0)), o1 = f2bf(v.y - bf2f(h1));
      unsigned short o2 = f2bf(v.z - bf2f(h2)), o3 = f2bf(v.w - bf2f(h3));
      unsigned off = (unsigned)(row*256) + (((unsigned)(d0*2)) ^ ((unsigned)(row&7) << 4));
      uint2 hu, lu;
      hu.x = (unsigned)h0 | ((unsigned)h1<<16); hu.y = (unsigned)h2 | ((unsigned)h3<<16);
      lu.x = (unsigned)o0 | ((unsigned)o1<<16); lu.y = (unsigned)o2 | ((unsigned)o3<<16);
      *(uint2*)(KH + off) = hu;
      *(uint2*)(KL + off) = lu;
    }
  }
  __syncthreads();

  // ---- load Q fragments to registers ----
  s8v qh[4], ql[4];
  {
    const int qrow = 16*wv + l15;
    const unsigned qswz = ((unsigned)(qrow & 7)) << 4;
    #pragma unroll
    for (int k0i = 0; k0i < 4; ++k0i) {
      unsigned off = (unsigned)(qrow*256) + (((unsigned)((k0i*4 + g)*16)) ^ qswz);
      union { uint4 u; s8v s; } a, b;
      a.u = *(const uint4*)(KH + off);
      b.u = *(const uint4*)(KL + off);
      qh[k0i] = a.s; ql[k0i] = b.s;
    }
  }

  float mo[4], ll[4], plr[4];
  #pragma unroll
  for (int r = 0; r < 4; ++r) {
    mo[r] = -1e30f; ll[r] = 0.0f;
    plr[r] = PL[(size_t)h * N + q0 + 16*wv + 4*g + r];
  }
  f4v oacc[8];
  #pragma unroll
  for (int t = 0; t < 8; ++t) oacc[t] = (f4v){0.f, 0.f, 0.f, 0.f};

  const unsigned kswz = ((unsigned)(l15 & 7)) << 4;

  for (int kt = 0; kt < NT; ++kt) {
    __syncthreads();   // prev PV / Q-frag reads done; LDS reusable

    // ---- stage Kh, Kl (bf16 global, swizzled b128 writes) ----
    {
      const unsigned short* khg = Khg + hqk + (size_t)(kt*TK) * Dh;
      const unsigned short* klg = Klg + hqk + (size_t)(kt*TK) * Dh;
      #pragma unroll
      for (int it = 0; it < 4; ++it) {
        int f = tid + 256*it;
        int row = f >> 4, sl = f & 15;
        unsigned off = (unsigned)(row*256) + (((unsigned)(sl*16)) ^ ((unsigned)(row&7) << 4));
        *(uint4*)(KH + off) = *(const uint4*)(khg + row*Dh + sl*8);
        *(uint4*)(KL + off) = *(const uint4*)(klg + row*Dh + sl*8);
      }
      // ---- stage Vt tile: 128 d-rows x 64 c-cols bf16, XOR swz ----
      const unsigned short* vtg = Vtg + (size_t)h*((size_t)Dh*N) + (size_t)(kt*TK);
      #pragma unroll
      for (int it = 0; it < 4; ++it) {
        int f = tid + 256*it;
        int d = f >> 3, sl = f & 7;
        unsigned off = (unsigned)(d*128) + (((unsigned)(sl*16)) ^ ((unsigned)(d&7) << 4));
        *(uint4*)(VT + off) = *(const uint4*)(vtg + (size_t)d*N + sl*8);
      }
    }
    __syncthreads();

    // ---- QK^T: 3-product split-bf16 MFMA ----
    f4v S[4];
    #pragma unroll
    for (int t = 0; t < 4; ++t) S[t] = (f4v){0.f, 0.f, 0.f, 0.f};
    #pragma unroll
    for (int k0i = 0; k0i < 4; ++k0i) {
      #pragma unroll
      for (int t = 0; t < 4; ++t) {
        unsigned off = (unsigned)(t*4096 + l15*256) + (((unsigned)((k0i*4 + g)*16)) ^ kswz);
        union { uint4 u; s8v s; } kh_, kl_;
        kh_.u = *(const uint4*)(KH + off);
        kl_.u = *(const uint4*)(KL + off);
        S[t] = __builtin_amdgcn_mfma_f32_16x16x32_bf16(qh[k0i], kh_.s, S[t], 0, 0, 0);
        S[t] = __builtin_amdgcn_mfma_f32_16x16x32_bf16(qh[k0i], kl_.s, S[t], 0, 0, 0);
        S[t] = __builtin_amdgcn_mfma_f32_16x16x32_bf16(ql[k0i], kh_.s, S[t], 0, 0, 0);
      }
    }

    // ---- online softmax (in-register, 16-lane butterflies) ----
    float sc[4], wq[4], p[4][4];
    #pragma unroll
    for (int r = 0; r < 4; ++r) {
      float v = fmaxf(fmaxf(S[0][r], S[1][r]), fmaxf(S[2][r], S[3][r]));
      v = fmaxf(v, __shfl_xor(v, 1)); v = fmaxf(v, __shfl_xor(v, 2));
      v = fmaxf(v, __shfl_xor(v, 4)); v = fmaxf(v, __shfl_xor(v, 8));
      float mn = fmaxf(mo[r], v);
      sc[r] = __expf(mo[r] - mn);
      wq[r] = __expf(mn - plr[r]);
      mo[r] = mn;
    }
    #pragma unroll
    for (int r = 0; r < 4; ++r) {
      float rs = 0.f;
      #pragma unroll
      for (int t = 0; t < 4; ++t) { float pv = __expf(S[t][r] - mo[r]); p[t][r] = pv; rs += pv; }
      rs += __shfl_xor(rs, 1); rs += __shfl_xor(rs, 2);
      rs += __shfl_xor(rs, 4); rs += __shfl_xor(rs, 8);
      ll[r] = ll[r]*sc[r] + rs;
    }
    // colsum partials (exact: p * exp(m - prev_l) = exp(s - prev_l))
    #pragma unroll
    for (int t = 0; t < 4; ++t) {
      float cv = p[t][0]*wq[0] + p[t][1]*wq[1] + p[t][2]*wq[2] + p[t][3]*wq[3];
      cv += __shfl_xor(cv, 16); cv += __shfl_xor(cv, 32);
      if (ln < 16) CSR[wv*64 + 16*t + ln] = cv;
    }
    // rescale O accumulator
    #pragma unroll
    for (int t = 0; t < 8; ++t) {
      f4v o = oacc[t];
      o[0] *= sc[0]; o[1] *= sc[1]; o[2] *= sc[2]; o[3] *= sc[3];
      oacc[t] = o;
    }
    // write P~ bf16 (swizzled)
    #pragma unroll
    for (int r = 0; r < 4; ++r) {
      int qlr = 4*g + r;
      unsigned key = ((unsigned)((qlr >> 1) & 7)) << 4;
      char* rowp = PB + wv*2048 + qlr*128;
      #pragma unroll
      for (int t = 0; t < 4; ++t) {
        unsigned off = ((unsigned)(32*t + 2*l15)) ^ key;
        *(unsigned short*)(rowp + off) = f2bf(p[t][r]);
      }
    }
    __syncthreads();

    // block-level colsum reduce (fixed order) -> global
    if (tid < 64) {
      float c0 = CSR[tid] + CSR[64 + tid] + CSR[128 + tid] + CSR[192 + tid];
      csPart[((size_t)h*NQB + qb)*N + kt*TK + tid] = c0;
    }

    // ---- PV: P(bf16) x V(bf16) with plain swizzled b128 reads ----
    {
      const unsigned pkey = ((unsigned)((l15 >> 1) & 7)) << 4;
      const char* prow = PB + wv*2048 + l15*128;
      union { uint4 u; s8v s; } pa0u, pa1u;
      pa0u.u = *(const uint4*)(prow + (((unsigned)(16*g)) ^ pkey));
      pa1u.u = *(const uint4*)(prow + (((unsigned)(64 + 16*g)) ^ pkey));
      s8v pa0 = pa0u.s, pa1 = pa1u.s;
      const unsigned vkey = ((unsigned)(l15 & 7)) << 4;
      #pragma unroll
      for (int t = 0; t < 8; ++t) {
        const char* vrow = VT + (16*t + l15)*128;
        union { uint4 u; s8v s; } b0, b1;
        b0.u = *(const uint4*)(vrow + (((unsigned)(16*g)) ^ vkey));
        b1.u = *(const uint4*)(vrow + (((unsigned)(64 + 16*g)) ^ vkey));
        oacc[t] = __builtin_amdgcn_mfma_f32_16x16x32_bf16(pa0, b0.s, oacc[t], 0, 0, 0);
        oacc[t] = __builtin_amdgcn_mfma_f32_16x16x32_bf16(pa1, b1.s, oacc[t], 0, 0, 0);
      }
    }
  }

  // ---- epilogue: O = oacc / l ----
  {
    float inv[4];
    #pragma unroll
    for (int r = 0; r < 4; ++r) inv[r] = 1.0f / ll[r];
    #pragma unroll
    for (int t = 0; t < 8; ++t) {
      #pragma unroll
      for (int r = 0; r < 4; ++r) {
        int row = q0 + 16*wv + 4*g + r;
        Out[hqk + (size_t)row*Dh + 16*t + l15] = oacc[t][r] * inv[r];
      }
    }
  }
}

// ----------------- fallback fp32 dense flash (proven R1) --------------------
__global__ __launch_bounds__(256, 1) void dense_attn_kernel(
    const float* __restrict__ Qm, const float* __restrict__ Km,
    const float* __restrict__ Vm, const float* __restrict__ PL,
    float* __restrict__ Out, float* __restrict__ csPart)
{
  extern __shared__ float sm[];
  float* qs   = sm;
  float* ks   = qs + BQ*Dh;
  float* vs   = ks + TK*Dh;
  float* pT   = vs + TK*Dh;
  float* redA = pT + TK*PT_LD;
  float* redB = redA + 16*64;
  float* redC = redB + 16*64;
  float* mrow = redC + 16*68;
  float* lrow = mrow + 64;
  float* srow = lrow + 64;
  float* wrow = srow + 64;
  float* plr  = wrow + 64;

  const int qb  = blockIdx.x;
  const int h   = blockIdx.y;
  const int q0  = qb * BQ;
  const int tid = threadIdx.x;
  const int tq  = tid & 15;
  const int tk4 = tid >> 4;
  const int swq = tq & 7;
  const int swk = tk4 & 7;

  const float* qg = Qm + (size_t)h * HEAD_STRIDE + (size_t)q0 * Dh;
  #pragma unroll
  for (int it = 0; it < 8; ++it) {
    int f = tid + 256*it;
    int row = f >> 5, d4 = f & 31;
    int e4 = d4 ^ ((row >> 2) & 7);
    float4 val = *(const float4*)(qg + row*Dh + (e4 << 2));
    val.x *= SCALE; val.y *= SCALE; val.z *= SCALE; val.w *= SCALE;
    *(float4*)(qs + row*Dh + (d4 << 2)) = val;
  }
  if (tid < 64) {
    mrow[tid] = -1e30f; lrow[tid] = 0.0f;
    plr[tid]  = PL[(size_t)h * N + q0 + tid];
  }
  float oacc[4][8];
  #pragma unroll
  for (int i = 0; i < 4; ++i)
    #pragma unroll
    for (int j = 0; j < 8; ++j) oacc[i][j] = 0.0f;

  for (int kt = 0; kt < NT; ++kt) {
    __syncthreads();
    const float* kg = Km + (size_t)h * HEAD_STRIDE + (size_t)(kt*TK) * Dh;
    const float* vg = Vm + (size_t)h * HEAD_STRIDE + (size_t)(kt*TK) * Dh;
    #pragma unroll
    for (int it = 0; it < 8; ++it) {
      int f = tid + 256*it;
      int row = f >> 5, d4 = f & 31;
      int e4 = d4 ^ ((row >> 2) & 7);
      *(float4*)(ks + row*Dh + (d4 << 2)) = *(const float4*)(kg + row*Dh + (e4 << 2));
      *(float4*)(vs + row*Dh + (d4 << 2)) = *(const float4*)(vg + row*Dh + (d4 << 2));
    }
    __syncthreads();

    float acc[4][4];
    #pragma unroll
    for (int i = 0; i < 4; ++i)
      #pragma unroll
      for (int j = 0; j < 4; ++j) acc[i][j] = 0.0f;
    for (int d4 = 0; d4 < 32; ++d4) {
      const int qo = ((d4 ^ swq) << 2);
      const int ko = ((d4 ^ swk) << 2);
      float4 qv[4], kv[4];
      #pragma unroll
      for (int i = 0; i < 4; ++i) qv[i] = *(const float4*)(qs + (4*tq + i)*Dh + qo);
      #pragma unroll
      for (int j = 0; j < 4; ++j) kv[j] = *(const float4*)(ks + (4*tk4 + j)*Dh + ko);
      #pragma unroll
      for (int i = 0; i < 4; ++i)
        #pragma unroll
        for (int j = 0; j < 4; ++j)
          acc[i][j] += qv[i].x*kv[j].x + qv[i].y*kv[j].y + qv[i].z*kv[j].z + qv[i].w*kv[j].w;
    }
    #pragma unroll
    for (int i = 0; i < 4; ++i) {
      float rm = fmaxf(fmaxf(acc[i][0], acc[i][1]), fmaxf(acc[i][2], acc[i][3]));
      redA[tk4*64 + 4*tq + i] = rm;
    }
    __syncthreads();
    if (tid < 64) {
      float m0 = redA[tid];
      #pragma unroll
      for (int t = 1; t < 16; ++t) m0 = fmaxf(m0, redA[t*64 + tid]);
      float mo_ = mrow[tid];
      float mn = fmaxf(mo_, m0);
      srow[tid] = __expf(mo_ - mn);
      mrow[tid] = mn;
      wrow[tid] = __expf(mn - plr[tid]);
    }
    __syncthreads();

    float mni[4], wi[4];
    #pragma unroll
    for (int i = 0; i < 4; ++i) { mni[i] = mrow[4*tq + i]; wi[i] = wrow[4*tq + i]; }
    float rs[4] = {0.f,0.f,0.f,0.f};
    float cl[4] = {0.f,0.f,0.f,0.f};
    float pv_[4][4];
    #pragma unroll
    for (int i = 0; i < 4; ++i)
      #pragma unroll
      for (int j = 0; j < 4; ++j) {
        float pv = __expf(acc[i][j] - mni[i]);
        pv_[i][j] = pv; rs[i] += pv; cl[j] += pv * wi[i];
      }
    #pragma unroll
    for (int j = 0; j < 4; ++j) {
      float4 pj; pj.x = pv_[0][j]; pj.y = pv_[1][j]; pj.z = pv_[2][j]; pj.w = pv_[3][j];
      *(float4*)(pT + (4*tk4 + j)*PT_LD + 4*tq) = pj;
    }
    #pragma unroll
    for (int i = 0; i < 4; ++i) redB[tk4*64 + 4*tq + i] = rs[i];
    #pragma unroll
    for (int j = 0; j < 4; ++j) redC[tq*68 + 4*tk4 + j] = cl[j];
    __syncthreads();
    if (tid < 64) {
      float s0 = redB[tid];
      #pragma unroll
      for (int t = 1; t < 16; ++t) s0 += redB[t*64 + tid];
      lrow[tid] = lrow[tid]*srow[tid] + s0;
      float c0 = redC[tid];
      #pragma unroll
      for (int t = 1; t < 16; ++t) c0 += redC[t*68 + tid];
      csPart[((size_t)h*NQB + qb)*N + kt*TK + tid] = c0;
    }

    float scl[4];
    #pragma unroll
    for (int i = 0; i < 4; ++i) scl[i] = srow[4*tq + i];
    #pragma unroll
    for (int i = 0; i < 4; ++i)
      #pragma unroll
      for (int j = 0; j < 8; ++j) oacc[i][j] *= scl[i];
    for (int kk = 0; kk < TK; ++kk) {
      float4 p4 = *(const float4*)(pT + kk*PT_LD + 4*tq);
      float4 va = *(const float4*)(vs + kk*Dh + (tk4 << 3));
      float4 vb = *(const float4*)(vs + kk*Dh + (tk4 << 3) + 4);
      float p_[4]; p_[0]=p4.x; p_[1]=p4.y; p_[2]=p4.z; p_[3]=p4.w;
      float v_[8]; v_[0]=va.x; v_[1]=va.y; v_[2]=va.z; v_[3]=va.w;
                   v_[4]=vb.x; v_[5]=vb.y; v_[6]=vb.z; v_[7]=vb.w;
      #pragma unroll
      for (int i = 0; i < 4; ++i)
        #pragma unroll
        for (int j = 0; j < 8; ++j) oacc[i][j] += p_[i] * v_[j];
    }
  }

  __syncthreads();
  #pragma unroll
  for (int i = 0; i < 4; ++i) {
    float inv = 1.0f / lrow[4*tq + i];
    size_t off = (size_t)h * HEAD_STRIDE + (size_t)(q0 + 4*tq + i) * Dh + (tk4 << 3);
    float4 a, b;
    a.x = oacc[i][0]*inv; a.y = oacc[i][1]*inv; a.z = oacc[i][2]*inv; a.w = oacc[i][3]*inv;
    b.x = oacc[i][4]*inv; b.y = oacc[i][5]*inv; b.z = oacc[i][6]*inv; b.w = oacc[i][7]*inv;
    *(float4*)(Out + off)     = a;
    *(float4*)(Out + off + 4) = b;
  }
}

// --------- selection: radix top-k + exact fp32 window + random mask ---------
__global__ __launch_bounds__(256) void select_kernel(
    const float* __restrict__ csPart, const int* __restrict__ topkPtr,
    const float* __restrict__ Qm, const float* __restrict__ Km,
    const float* __restrict__ PL,
    int* __restrict__ idxList, int* __restrict__ nSel)
{
  __shared__ uint32_t ubits[N];
  __shared__ int hist[256];
  __shared__ int cnt1[256], base1[256];
  __shared__ int sh_digit, sh_kk, sh_total, sh_A, sh_C;
  __shared__ float kcol[128];
  __shared__ float exacc[4];
  __shared__ int candIdx[CAND_MAX];
  __shared__ float candEx[CAND_MAX];
  __shared__ unsigned char candSel[CAND_MAX];
  __shared__ unsigned char selmap[N];

  const int bh = blockIdx.x;
  const int h = bh >> 4, g = bh & 15;
  const int tid = threadIdx.x;

  const float* p0 = csPart + ((size_t)h*NQB + 3*g) * N;
  for (int c = tid; c < N; c += 256) {
    float v = p0[c] + p0[N + c] + p0[2*(size_t)N + c];
    ubits[c] = __float_as_uint(v);
    selmap[c] = 0;
  }
  __syncthreads();

  const int K = topkPtr[0];
  uint32_t prefix = 0; int kk = K;
  for (int pass = 0; pass < 4; ++pass) {
    const int shift = 24 - 8*pass;
    const uint32_t hm = (pass == 0) ? 0u : (0xFFFFFFFFu << (shift + 8));
    hist[tid] = 0;
    __syncthreads();
    for (int c = tid; c < N; c += 256) {
      uint32_t b = ubits[c];
      if ((b & hm) == (prefix & hm)) atomicAdd(&hist[(b >> shift) & 255], 1);
    }
    __syncthreads();
    if (tid == 0) {
      int cum = 0, d = 255;
      for (; d > 0; --d) { int hc = hist[d]; if (cum + hc >= kk) break; cum += hc; }
      sh_digit = d; sh_kk = kk - cum;
    }
    __syncthreads();
    prefix |= ((uint32_t)sh_digit) << shift;
    kk = sh_kk;
    __syncthreads();
  }
  const float thrv = __uint_as_float(prefix);   // coarse K-th largest (cs > 0)
  const float hiv  = thrv * 1.001f;
  const float lov  = thrv * 0.999f;

  // classify: definite-in (A) vs candidates (window)
  if (tid == 0) { sh_A = 0; sh_C = 0; }
  __syncthreads();
  const int CH = N / 256;
  const int c0 = tid * CH;
  int myIn = 0;
  for (int j = 0; j < CH; ++j) {
    float v = __uint_as_float(ubits[c0 + j]);
    if (v > hiv) myIn++;
    else if (v >= lov) {
      int slot = atomicAdd(&sh_C, 1);
      if (slot < CAND_MAX) candIdx[slot] = c0 + j;
    }
  }
  atomicAdd(&sh_A, myIn);
  __syncthreads();
  const int A = sh_A;
  const int C = min(sh_C, CAND_MAX);
  int need = K - A;
  if (need < 0) need = 0;
  if (need > C) need = C;

  // exact fp32 recompute of candidate colsums
  const float* Qg = Qm + (size_t)h*HEAD_STRIDE + (size_t)(g*192)*Dh;
  const float* Kg = Km + (size_t)h*HEAD_STRIDE;
  const float  plq = (tid < 192) ? PL[(size_t)h*N + g*192 + tid] : 0.f;
  for (int ci = 0; ci < C; ++ci) {
    int c = candIdx[ci];
    if (tid < 128) kcol[tid] = Kg[(size_t)c*Dh + tid];
    __syncthreads();
    float e = 0.f;
    if (tid < 192) {
      const float* qr = Qg + (size_t)tid*Dh;
      float acc = 0.f;
      #pragma unroll
      for (int d4 = 0; d4 < 32; ++d4) {
        float4 qv = *(const float4*)(qr + d4*4);
        acc += qv.x*kcol[d4*4] + qv.y*kcol[d4*4+1] + qv.z*kcol[d4*4+2] + qv.w*kcol[d4*4+3];
      }
      e = expf(acc*SCALE - plq);
    }
    #pragma unroll
    for (int s = 1; s < 64; s <<= 1) e += __shfl_xor(e, s);
    if ((tid & 63) == 0) exacc[tid >> 6] = e;
    __syncthreads();
    if (tid == 0) candEx[ci] = (exacc[0] + exacc[1]) + (exacc[2] + exacc[3]);
    __syncthreads();
  }

  // rank candidates by (exact desc, idx asc); select first `need`
  if (tid < C) {
    float ei = candEx[tid]; int ii = candIdx[tid];
    int rank = 0;
    for (int j = 0; j < C; ++j) {
      float ej = candEx[j];
      if (ej > ei || (ej == ei && candIdx[j] < ii)) ++rank;
    }
    candSel[tid] = (rank < need) ? 1 : 0;
  }
  __syncthreads();
  if (tid < C && candSel[tid]) selmap[candIdx[tid]] = 1;
  __syncthreads();

  // final flags: definite-in | selected candidate | random
  bool fl[12]; int selc = 0;
  for (int j = 0; j < CH; ++j) {
    int c = c0 + j;
    float v = __uint_as_float(ubits[c]);
    bool s = (v > hiv) || (selmap[c] != 0);
    if (!s) s = jax_rand_zero((uint32_t)bh * (uint32_t)N + (uint32_t)c);
    fl[j] = s; selc += s ? 1 : 0;
  }
  cnt1[tid] = selc;
  __syncthreads();
  if (tid == 0) { int run = 0; for (int t = 0; t < 256; ++t) { base1[t] = run; run += cnt1[t]; } sh_total = run; }
  __syncthreads();
  int w = base1[tid];
  int* il = idxList + (size_t)bh * IDXCAP;
  for (int j = 0; j < CH; ++j) if (fl[j]) { if (w < IDXCAP) il[w] = c0 + j; ++w; }
  if (tid == 0) nSel[bh] = (sh_total < IDXCAP) ? sh_total : IDXCAP;
}

// ----------------------- sparse flash + out_cache ---------------------------
__global__ __launch_bounds__(256, 1) void sparse_attn_kernel(
    const float* __restrict__ Qm, const float* __restrict__ Km,
    const float* __restrict__ Vm, const int* __restrict__ idxList,
    const int* __restrict__ nSel, float* __restrict__ Out)
{
  extern __shared__ float sm[];
  float* qs   = sm;
  float* ks   = qs + BQ*Dh;
  float* vs   = ks + TK*Dh;
  float* pT   = vs + TK*Dh;
  float* redA = pT + TK*PT_LD;
  float* redB = redA + 16*64;
  float* mrow = redB + 16*64;
  float* lrow = mrow + 64;
  float* srow = lrow + 64;
  int*   idxs = (int*)(srow + 64);

  const int qb  = blockIdx.x;
  const int h   = blockIdx.y;
  const int g   = qb / 3;
  const int q0  = qb * BQ;
  const int tid = threadIdx.x;
  const int tq  = tid & 15;
  const int tk4 = tid >> 4;
  const int swq = tq & 7;
  const int swk = tk4 & 7;

  int nsel = nSel[h*M + g];
  if (nsel > IDXCAP) nsel = IDXCAP;
  const int* il = idxList + ((size_t)h*M + g) * IDXCAP;

  const float* qg = Qm + (size_t)h * HEAD_STRIDE + (size_t)q0 * Dh;
  #pragma unroll
  for (int it = 0; it < 8; ++it) {
    int f = tid + 256*it;
    int row = f >> 5, d4 = f & 31;
    int e4 = d4 ^ ((row >> 2) & 7);
    float4 val = *(const float4*)(qg + row*Dh + (e4 << 2));
    val.x *= SCALE; val.y *= SCALE; val.z *= SCALE; val.w *= SCALE;
    *(float4*)(qs + row*Dh + (d4 << 2)) = val;
  }
  if (tid < 64) { mrow[tid] = -1e30f; lrow[tid] = 0.0f; }

  float oacc[4][8];
  #pragma unroll
  for (int i = 0; i < 4; ++i)
    #pragma unroll
    for (int j = 0; j < 8; ++j) oacc[i][j] = 0.0f;

  const int nt = (nsel + TK - 1) / TK;
  const float* kb = Km + (size_t)h * HEAD_STRIDE;
  const float* vb = Vm + (size_t)h * HEAD_STRIDE;

  for (int t = 0; t < nt; ++t) {
    const int cnt = min(TK, nsel - t*TK);
    __syncthreads();
    if (tid < 64) idxs[tid] = (tid < cnt) ? il[t*TK + tid] : 0;
    __syncthreads();
    #pragma unroll
    for (int it = 0; it < 8; ++it) {
      int f = tid + 256*it;
      int row = f >> 5, d4 = f & 31;
      int e4 = d4 ^ ((row >> 2) & 7);
      int c  = idxs[row];
      *(float4*)(ks + row*Dh + (d4 << 2)) = *(const float4*)(kb + (size_t)c*Dh + (e4 << 2));
      *(float4*)(vs + row*Dh + (d4 << 2)) = *(const float4*)(vb + (size_t)c*Dh + (d4 << 2));
    }
    __syncthreads();

    float acc[4][4];
    #pragma unroll
    for (int i = 0; i < 4; ++i)
      #pragma unroll
      for (int j = 0; j < 4; ++j) acc[i][j] = 0.0f;
    for (int d4 = 0; d4 < 32; ++d4) {
      const int qo = ((d4 ^ swq) << 2);
      const int ko = ((d4 ^ swk) << 2);
      float4 qv[4], kv[4];
      #pragma unroll
      for (int i = 0; i < 4; ++i) qv[i] = *(const float4*)(qs + (4*tq + i)*Dh + qo);
      #pragma unroll
      for (int j = 0; j < 4; ++j) kv[j] = *(const float4*)(ks + (4*tk4 + j)*Dh + ko);
      #pragma unroll
      for (int i = 0; i < 4; ++i)
        #pragma unroll
        for (int j = 0; j < 4; ++j)
          acc[i][j] += qv[i].x*kv[j].x + qv[i].y*kv[j].y + qv[i].z*kv[j].z + qv[i].w*kv[j].w;
    }
    #pragma unroll
    for (int j = 0; j < 4; ++j)
      if (4*tk4 + j >= cnt) { acc[0][j] = acc[1][j] = acc[2][j] = acc[3][j] = -1e30f; }

    #pragma unroll
    for (int i = 0; i < 4; ++i) {
      float rm = fmaxf(fmaxf(acc[i][0], acc[i][1]), fmaxf(acc[i][2], acc[i][3]));
      redA[tk4*64 + 4*tq + i] = rm;
    }
    __syncthreads();
    if (tid < 64) {
      float m0 = redA[tid];
      #pragma unroll
      for (int tt = 1; tt < 16; ++tt) m0 = fmaxf(m0, redA[tt*64 + tid]);
      float mo_ = mrow[tid];
      float mn = fmaxf(mo_, m0);
      srow[tid] = __expf(mo_ - mn);
      mrow[tid] = mn;
    }
    __syncthreads();

    float mni[4];
    #pragma unroll
    for (int i = 0; i < 4; ++i) mni[i] = mrow[4*tq + i];
    float rs[4] = {0.f,0.f,0.f,0.f};
    float pv_[4][4];
    #pragma unroll
    for (int i = 0; i < 4; ++i)
      #pragma unroll
      for (int j = 0; j < 4; ++j) {
        float pv = __expf(acc[i][j] - mni[i]);
        pv_[i][j] = pv; rs[i] += pv;
      }
    #pragma unroll
    for (int j = 0; j < 4; ++j) {
      float4 pj; pj.x = pv_[0][j]; pj.y = pv_[1][j]; pj.z = pv_[2][j]; pj.w = pv_[3][j];
      *(float4*)(pT + (4*tk4 + j)*PT_LD + 4*tq) = pj;
    }
    #pragma unroll
    for (int i = 0; i < 4; ++i) redB[tk4*64 + 4*tq + i] = rs[i];
    __syncthreads();
    if (tid < 64) {
      float s0 = redB[tid];
      #pragma unroll
      for (int tt = 1; tt < 16; ++tt) s0 += redB[tt*64 + tid];
      lrow[tid] = lrow[tid]*srow[tid] + s0;
    }

    float scl[4];
    #pragma unroll
    for (int i = 0; i < 4; ++i) scl[i] = srow[4*tq + i];
    #pragma unroll
    for (int i = 0; i < 4; ++i)
      #pragma unroll
      for (int j = 0; j < 8; ++j) oacc[i][j] *= scl[i];
    for (int kk = 0; kk < TK; ++kk) {
      float4 p4 = *(const float4*)(pT + kk*PT_LD + 4*tq);
      float4 va = *(const float4*)(vs + kk*Dh + (tk4 << 3));
      float4 vbv = *(const float4*)(vs + kk*Dh + (tk4 << 3) + 4);
      float p_[4]; p_[0]=p4.x; p_[1]=p4.y; p_[2]=p4.z; p_[3]=p4.w;
      float v_[8]; v_[0]=va.x; v_[1]=va.y; v_[2]=va.z; v_[3]=va.w;
                   v_[4]=vbv.x; v_[5]=vbv.y; v_[6]=vbv.z; v_[7]=vbv.w;
      #pragma unroll
      for (int i = 0; i < 4; ++i)
        #pragma unroll
        for (int j = 0; j < 8; ++j) oacc[i][j] += p_[i] * v_[j];
    }
  }

  __syncthreads();
  #pragma unroll
  for (int i = 0; i < 4; ++i) {
    float inv = 1.0f / lrow[4*tq + i];
    size_t off = (size_t)h * HEAD_STRIDE + (size_t)(q0 + 4*tq + i) * Dh + (tk4 << 3);
    float4 oa = *(const float4*)(Out + off);
    float4 ob = *(const float4*)(Out + off + 4);
    float4 ca, cb;
    ca.x = oa.x - oacc[i][0]*inv; ca.y = oa.y - oacc[i][1]*inv;
    ca.z = oa.z - oacc[i][2]*inv; ca.w = oa.w - oacc[i][3]*inv;
    cb.x = ob.x - oacc[i][4]*inv; cb.y = ob.y - oacc[i][5]*inv;
    cb.z = ob.z - oacc[i][6]*inv; cb.w = ob.w - oacc[i][7]*inv;
    *(float4*)(Out + OUT_HALF + off)     = ca;
    *(float4*)(Out + OUT_HALF + off + 4) = cb;
  }
}

// ------------------------------- launch -------------------------------------
extern "C" void kernel_launch(void* const* d_in, const int* in_sizes, int n_in,
                              void* d_out, int out_size, void* d_ws, size_t ws_size,
                              hipStream_t stream) {
  const float* q  = (const float*)d_in[0];
  const float* k  = (const float*)d_in[1];
  const float* v  = (const float*)d_in[2];
  const float* pl = (const float*)d_in[3];
  const int* topk = (const int*)d_in[4];
  float* out = (float*)d_out;
  char* ws   = (char*)d_ws;

  float* csPart = (float*)(ws + CS_B);
  int*   idxL   = (int*)(ws + IDX_B);
  int*   nSel   = (int*)(ws + NSEL_B);

  (void)hipFuncSetAttribute((const void*)dense_mfma_kernel,
      hipFuncAttributeMaxDynamicSharedMemorySize, MFMA_SM);
  (void)hipFuncSetAttribute((const void*)dense_attn_kernel,
      hipFuncAttributeMaxDynamicSharedMemorySize, DENSE_SM * 4);
  (void)hipFuncSetAttribute((const void*)sparse_attn_kernel,
      hipFuncAttributeMaxDynamicSharedMemorySize, SPARSE_SM * 4);

  if (ws_size >= NEED_B) {
    unsigned short* Kh = (unsigned short*)(ws + KH_B);
    unsigned short* Kl = (unsigned short*)(ws + KL_B);
    unsigned short* Vt = (unsigned short*)(out + OUT_HALF);  // scratch; sparse overwrites later
    split_bf16_kernel<<<6144, 256, 0, stream>>>(k, Kh, Kl);
    transpose_v_kernel<<<dim3(H, N/64), 256, 0, stream>>>(v, Vt);
    dense_mfma_kernel<<<768, 256, MFMA_SM, stream>>>(q, Kh, Kl, Vt, pl, out, csPart);
  } else {
    dense_attn_kernel<<<dim3(NQB, H), 256, DENSE_SM * 4, stream>>>(q, k, v, pl, out, csPart);
  }
  select_kernel<<<dim3(H * M), 256, 0, stream>>>(csPart, topk, q, k, pl, idxL, nSel);
  sparse_attn_kernel<<<dim3(NQB, H), 256, SPARSE_SM * 4, stream>>>(q, k, v, idxL, nSel, out);
}

// Round 5
// 600.126 us; speedup vs baseline: 3.6914x; 1.4846x over previous
//
#include <hip/hip_runtime.h>
#include <stdint.h>

// ---------------------------------------------------------------------------
// SparseDiffAttention R4: dense flash attn on MFMA (split-bf16 QK, bf16 PV via
// pre-transposed Vt) + coarse colsum -> select with exact fp32 recompute of
// near-threshold candidates (+threefry random cols) -> sparse MFMA flash
// (gathered split-bf16 K, LDS-transposed bf16 V) -> out = stack([o, o - spo]).
// ---------------------------------------------------------------------------

#define JAX_PARTITIONABLE 1

namespace {
constexpr int H   = 16;
constexpr int N   = 3072;
constexpr int Dh  = 128;
constexpr int M   = 16;
constexpr int BQ  = 64;
constexpr int TK  = 64;
constexpr int NQB = N / BQ;        // 48
constexpr int NT  = N / TK;        // 48
constexpr float SCALE = 0.08838834764831845f;
constexpr size_t HEAD_STRIDE = (size_t)N * Dh;
constexpr size_t OUT_HALF    = (size_t)H * N * Dh;

constexpr int PT_LD = BQ + 4;
constexpr int IDXCAP = 1024;       // max selected columns per group
constexpr int CAND_MAX = 128;

// fallback fp32 dense / sparse kernel LDS (floats)
constexpr int DENSE_SM  = 3*BQ*Dh + TK*PT_LD + 16*64 + 16*64 + 16*68 + 5*64;
constexpr int SPARSE_SM = 3*BQ*Dh + TK*PT_LD + 16*64 + 16*64 + 3*64 + 64;

// MFMA dense kernel LDS layout (bytes)
constexpr int KH_OFF = 0;          // 64x128 bf16, row stride 256B, XOR swz
constexpr int KL_OFF = 16384;
constexpr int VT_OFF = 32768;      // dense: 128(d) x 64(c) bf16, row 128B, swz
constexpr int PB_OFF = 49152;      // 4 waves x 16q x 64c bf16, XOR swz
constexpr int CSR_OFF = 57344;     // 4 x 64 f32
constexpr int MFMA_SM = 58368;

// sparse MFMA kernel LDS layout (bytes)
constexpr int SP_KH  = 0;          // 16384
constexpr int SP_KL  = 16384;      // 16384
constexpr int SP_VT  = 32768;      // [128 d][72 shorts] = 18432 (144B rows)
constexpr int SP_PB  = 51200;      // 8192
constexpr int SP_IDX = 59392;      // 64 ints
constexpr int SPMF_SM = 59648;

// ws layout (bytes)
constexpr size_t CS_B   = 0;                        // [H][NQB][N] f32 = 9.44MB
constexpr size_t IDX_B  = 9437184;                  // [H][M][IDXCAP] i32 = 1MB
constexpr size_t NSEL_B = IDX_B + (size_t)H*M*IDXCAP*4;   // 10,485,760
constexpr size_t KH_B   = NSEL_B + 1024;            // [H][N][Dh] bf16
constexpr size_t KL_B   = KH_B + 12582912;
constexpr size_t NEED_B = KL_B + 12582912;          // 35,652,608
}

typedef float f4v __attribute__((ext_vector_type(4)));
typedef short s8v __attribute__((ext_vector_type(8)));

__device__ __forceinline__ unsigned short f2bf(float x) {
  unsigned u = __float_as_uint(x);
  unsigned r = u + 0x7FFFu + ((u >> 16) & 1u);
  return (unsigned short)(r >> 16);
}
__device__ __forceinline__ float bf2f(unsigned short b) {
  return __uint_as_float(((unsigned)b) << 16);
}

// ------------------------------ threefry -----------------------------------
__device__ __forceinline__ void tf_round(uint32_t& x0, uint32_t& x1, int r) {
  x0 += x1; x1 = (x1 << r) | (x1 >> (32 - r)); x1 ^= x0;
}
__device__ __forceinline__ void tf2x32(uint32_t k0, uint32_t k1,
                                       uint32_t x0, uint32_t x1,
                                       uint32_t& y0, uint32_t& y1) {
  uint32_t k2 = k0 ^ k1 ^ 0x1BD11BDAu;
  x0 += k0; x1 += k1;
  tf_round(x0,x1,13); tf_round(x0,x1,15); tf_round(x0,x1,26); tf_round(x0,x1,6);
  x0 += k1; x1 += k2 + 1u;
  tf_round(x0,x1,17); tf_round(x0,x1,29); tf_round(x0,x1,16); tf_round(x0,x1,24);
  x0 += k2; x1 += k0 + 2u;
  tf_round(x0,x1,13); tf_round(x0,x1,15); tf_round(x0,x1,26); tf_round(x0,x1,6);
  x0 += k0; x1 += k1 + 3u;
  tf_round(x0,x1,17); tf_round(x0,x1,29); tf_round(x0,x1,16); tf_round(x0,x1,24);
  x0 += k1; x1 += k2 + 4u;
  tf_round(x0,x1,13); tf_round(x0,x1,15); tf_round(x0,x1,26); tf_round(x0,x1,6);
  x0 += k2; x1 += k0 + 5u;
  y0 = x0; y1 = x1;
}

__device__ __forceinline__ bool jax_rand_zero(uint32_t idx) {
  uint32_t hi, lo, r0, r1;
#if JAX_PARTITIONABLE
  uint32_t a0,a1,b0,b1;
  tf2x32(0u,42u, 0u,0u, a0,a1);
  tf2x32(0u,42u, 0u,1u, b0,b1);
  tf2x32(a0,a1, 0u, idx, r0,r1);  hi = r0 ^ r1;
  tf2x32(b0,b1, 0u, idx, r0,r1);  lo = r0 ^ r1;
#else
  uint32_t p0x,p0y,p1x,p1y;
  tf2x32(0u,42u, 0u,2u, p0x,p0y);
  tf2x32(0u,42u, 1u,3u, p1x,p1y);
  const uint32_t half = (uint32_t)((size_t)H*M*N) / 2u;
  uint32_t i = (idx < half) ? idx : (idx - half);
  uint32_t h0,h1,l0,l1;
  tf2x32(p0x, p1x, i, i + half, h0, h1);
  tf2x32(p0y, p1y, i, i + half, l0, l1);
  hi = (idx < half) ? h0 : h1;
  lo = (idx < half) ? l0 : l1;
#endif
  uint32_t off = ((hi % 100u) * 96u + (lo % 100u)) % 100u;
  return off == 0u;
}

// ----------------------- precompute: K -> Kh,Kl bf16 ------------------------
__global__ __launch_bounds__(256) void split_bf16_kernel(
    const float* __restrict__ K, unsigned short* __restrict__ Kh,
    unsigned short* __restrict__ Kl)
{
  size_t i = ((size_t)blockIdx.x * 256 + threadIdx.x) * 4;
  float4 v = *(const float4*)(K + i);
  unsigned short h0 = f2bf(v.x), h1 = f2bf(v.y), h2 = f2bf(v.z), h3 = f2bf(v.w);
  unsigned short l0 = f2bf(v.x - bf2f(h0)), l1 = f2bf(v.y - bf2f(h1));
  unsigned short l2 = f2bf(v.z - bf2f(h2)), l3 = f2bf(v.w - bf2f(h3));
  uint2 hu, lu;
  hu.x = (unsigned)h0 | ((unsigned)h1 << 16); hu.y = (unsigned)h2 | ((unsigned)h3 << 16);
  lu.x = (unsigned)l0 | ((unsigned)l1 << 16); lu.y = (unsigned)l2 | ((unsigned)l3 << 16);
  *(uint2*)(Kh + i) = hu;
  *(uint2*)(Kl + i) = lu;
}

// ----------------------- precompute: V -> Vt bf16 [H][Dh][N] ----------------
__global__ __launch_bounds__(256) void transpose_v_kernel(
    const float* __restrict__ Vm, unsigned short* __restrict__ Vt)
{
  __shared__ unsigned short tb[64][132];
  const int h  = blockIdx.x;
  const int cb = blockIdx.y;          // 64-col tile
  const int tid = threadIdx.x;
  const float* vg = Vm + (size_t)h*HEAD_STRIDE + (size_t)(cb*64)*Dh;
  #pragma unroll
  for (int it = 0; it < 8; ++it) {
    int f = tid + 256*it;
    int c = f >> 5, d0 = (f & 31)*4;
    float4 v = *(const float4*)(vg + c*Dh + d0);
    tb[c][d0+0] = f2bf(v.x); tb[c][d0+1] = f2bf(v.y);
    tb[c][d0+2] = f2bf(v.z); tb[c][d0+3] = f2bf(v.w);
  }
  __syncthreads();
  unsigned short* vt = Vt + (size_t)h*((size_t)Dh*N) + (size_t)(cb*64);
  #pragma unroll
  for (int it = 0; it < 4; ++it) {
    int f = tid + 256*it;
    int d = f >> 3, sl = f & 7;       // 8 slots of 8 c's per d-row
    union { unsigned short us[8]; uint4 u; } o;
    #pragma unroll
    for (int i = 0; i < 8; ++i) o.us[i] = tb[sl*8 + i][d];
    *(uint4*)(vt + (size_t)d*N + sl*8) = o.u;
  }
}

// --------------------------- dense MFMA flash -------------------------------
__global__ __launch_bounds__(256, 2) void dense_mfma_kernel(
    const float* __restrict__ Qm, const unsigned short* __restrict__ Khg,
    const unsigned short* __restrict__ Klg, const unsigned short* __restrict__ Vtg,
    const float* __restrict__ PL, float* __restrict__ Out,
    float* __restrict__ csPart)
{
  extern __shared__ char smc[];
  char* KH = smc + KH_OFF;
  char* KL = smc + KL_OFF;
  char* VT = smc + VT_OFF;
  char* PB = smc + PB_OFF;
  float* CSR = (float*)(smc + CSR_OFF);

  // XCD-chunked swizzle: 768 blocks, 8 XCDs, 96 per chunk
  const int id  = blockIdx.x;
  const int wid = (id & 7) * 96 + (id >> 3);
  const int h   = wid / NQB;
  const int qb  = wid % NQB;
  const int q0  = qb * BQ;

  const int tid = threadIdx.x;
  const int wv  = tid >> 6;
  const int ln  = tid & 63;
  const int g   = ln >> 4;
  const int l15 = ln & 15;

  const size_t hqk = (size_t)h * HEAD_STRIDE;

  // ---- stage Q (scaled, split hi/lo) into KH/KL regions ----
  {
    const float* qg = Qm + hqk + (size_t)q0 * Dh;
    #pragma unroll
    for (int it = 0; it < 8; ++it) {
      int f = tid + 256*it;
      int row = f >> 5, d0 = (f & 31) * 4;
      float4 v = *(const float4*)(qg + row*Dh + d0);
      v.x *= SCALE; v.y *= SCALE; v.z *= SCALE; v.w *= SCALE;
      unsigned short h0 = f2bf(v.x), h1 = f2bf(v.y), h2 = f2bf(v.z), h3 = f2bf(v.w);
      unsigned short o0 = f2bf(v.x - bf2f(h0)), o1 = f2bf(v.y - bf2f(h1));
      unsigned short o2 = f2bf(v.z - bf2f(h2)), o3 = f2bf(v.w - bf2f(h3));
      unsigned off = (unsigned)(row*256) + (((unsigned)(d0*2)) ^ ((unsigned)(row&7) << 4));
      uint2 hu, lu;
      hu.x = (unsigned)h0 | ((unsigned)h1<<16); hu.y = (unsigned)h2 | ((unsigned)h3<<16);
      lu.x = (unsigned)o0 | ((unsigned)o1<<16); lu.y = (unsigned)o2 | ((unsigned)o3<<16);
      *(uint2*)(KH + off) = hu;
      *(uint2*)(KL + off) = lu;
    }
  }
  __syncthreads();

  // ---- load Q fragments to registers ----
  s8v qh[4], ql[4];
  {
    const int qrow = 16*wv + l15;
    const unsigned qswz = ((unsigned)(qrow & 7)) << 4;
    #pragma unroll
    for (int k0i = 0; k0i < 4; ++k0i) {
      unsigned off = (unsigned)(qrow*256) + (((unsigned)((k0i*4 + g)*16)) ^ qswz);
      union { uint4 u; s8v s; } a, b;
      a.u = *(const uint4*)(KH + off);
      b.u = *(const uint4*)(KL + off);
      qh[k0i] = a.s; ql[k0i] = b.s;
    }
  }

  float mo[4], ll[4], plr[4];
  #pragma unroll
  for (int r = 0; r < 4; ++r) {
    mo[r] = -1e30f; ll[r] = 0.0f;
    plr[r] = PL[(size_t)h * N + q0 + 16*wv + 4*g + r];
  }
  f4v oacc[8];
  #pragma unroll
  for (int t = 0; t < 8; ++t) oacc[t] = (f4v){0.f, 0.f, 0.f, 0.f};

  const unsigned kswz = ((unsigned)(l15 & 7)) << 4;

  for (int kt = 0; kt < NT; ++kt) {
    __syncthreads();   // prev PV / Q-frag reads done; LDS reusable

    // ---- stage Kh, Kl (bf16 global, swizzled b128 writes) ----
    {
      const unsigned short* khg = Khg + hqk + (size_t)(kt*TK) * Dh;
      const unsigned short* klg = Klg + hqk + (size_t)(kt*TK) * Dh;
      #pragma unroll
      for (int it = 0; it < 4; ++it) {
        int f = tid + 256*it;
        int row = f >> 4, sl = f & 15;
        unsigned off = (unsigned)(row*256) + (((unsigned)(sl*16)) ^ ((unsigned)(row&7) << 4));
        *(uint4*)(KH + off) = *(const uint4*)(khg + row*Dh + sl*8);
        *(uint4*)(KL + off) = *(const uint4*)(klg + row*Dh + sl*8);
      }
      // ---- stage Vt tile: 128 d-rows x 64 c-cols bf16, XOR swz ----
      const unsigned short* vtg = Vtg + (size_t)h*((size_t)Dh*N) + (size_t)(kt*TK);
      #pragma unroll
      for (int it = 0; it < 4; ++it) {
        int f = tid + 256*it;
        int d = f >> 3, sl = f & 7;
        unsigned off = (unsigned)(d*128) + (((unsigned)(sl*16)) ^ ((unsigned)(d&7) << 4));
        *(uint4*)(VT + off) = *(const uint4*)(vtg + (size_t)d*N + sl*8);
      }
    }
    __syncthreads();

    // ---- QK^T: 3-product split-bf16 MFMA ----
    f4v S[4];
    #pragma unroll
    for (int t = 0; t < 4; ++t) S[t] = (f4v){0.f, 0.f, 0.f, 0.f};
    #pragma unroll
    for (int k0i = 0; k0i < 4; ++k0i) {
      #pragma unroll
      for (int t = 0; t < 4; ++t) {
        unsigned off = (unsigned)(t*4096 + l15*256) + (((unsigned)((k0i*4 + g)*16)) ^ kswz);
        union { uint4 u; s8v s; } kh_, kl_;
        kh_.u = *(const uint4*)(KH + off);
        kl_.u = *(const uint4*)(KL + off);
        S[t] = __builtin_amdgcn_mfma_f32_16x16x32_bf16(qh[k0i], kh_.s, S[t], 0, 0, 0);
        S[t] = __builtin_amdgcn_mfma_f32_16x16x32_bf16(qh[k0i], kl_.s, S[t], 0, 0, 0);
        S[t] = __builtin_amdgcn_mfma_f32_16x16x32_bf16(ql[k0i], kh_.s, S[t], 0, 0, 0);
      }
    }

    // ---- online softmax (in-register, 16-lane butterflies) ----
    float sc[4], wq[4], p[4][4];
    #pragma unroll
    for (int r = 0; r < 4; ++r) {
      float v = fmaxf(fmaxf(S[0][r], S[1][r]), fmaxf(S[2][r], S[3][r]));
      v = fmaxf(v, __shfl_xor(v, 1)); v = fmaxf(v, __shfl_xor(v, 2));
      v = fmaxf(v, __shfl_xor(v, 4)); v = fmaxf(v, __shfl_xor(v, 8));
      float mn = fmaxf(mo[r], v);
      sc[r] = __expf(mo[r] - mn);
      wq[r] = __expf(mn - plr[r]);
      mo[r] = mn;
    }
    #pragma unroll
    for (int r = 0; r < 4; ++r) {
      float rs = 0.f;
      #pragma unroll
      for (int t = 0; t < 4; ++t) { float pv = __expf(S[t][r] - mo[r]); p[t][r] = pv; rs += pv; }
      rs += __shfl_xor(rs, 1); rs += __shfl_xor(rs, 2);
      rs += __shfl_xor(rs, 4); rs += __shfl_xor(rs, 8);
      ll[r] = ll[r]*sc[r] + rs;
    }
    // colsum partials (exact: p * exp(m - prev_l) = exp(s - prev_l))
    #pragma unroll
    for (int t = 0; t < 4; ++t) {
      float cv = p[t][0]*wq[0] + p[t][1]*wq[1] + p[t][2]*wq[2] + p[t][3]*wq[3];
      cv += __shfl_xor(cv, 16); cv += __shfl_xor(cv, 32);
      if (ln < 16) CSR[wv*64 + 16*t + ln] = cv;
    }
    // rescale O accumulator
    #pragma unroll
    for (int t = 0; t < 8; ++t) {
      f4v o = oacc[t];
      o[0] *= sc[0]; o[1] *= sc[1]; o[2] *= sc[2]; o[3] *= sc[3];
      oacc[t] = o;
    }
    // write P~ bf16 (swizzled)
    #pragma unroll
    for (int r = 0; r < 4; ++r) {
      int qlr = 4*g + r;
      unsigned key = ((unsigned)((qlr >> 1) & 7)) << 4;
      char* rowp = PB + wv*2048 + qlr*128;
      #pragma unroll
      for (int t = 0; t < 4; ++t) {
        unsigned off = ((unsigned)(32*t + 2*l15)) ^ key;
        *(unsigned short*)(rowp + off) = f2bf(p[t][r]);
      }
    }
    __syncthreads();

    // block-level colsum reduce (fixed order) -> global
    if (tid < 64) {
      float c0 = CSR[tid] + CSR[64 + tid] + CSR[128 + tid] + CSR[192 + tid];
      csPart[((size_t)h*NQB + qb)*N + kt*TK + tid] = c0;
    }

    // ---- PV: P(bf16) x V(bf16) with plain swizzled b128 reads ----
    {
      const unsigned pkey = ((unsigned)((l15 >> 1) & 7)) << 4;
      const char* prow = PB + wv*2048 + l15*128;
      union { uint4 u; s8v s; } pa0u, pa1u;
      pa0u.u = *(const uint4*)(prow + (((unsigned)(16*g)) ^ pkey));
      pa1u.u = *(const uint4*)(prow + (((unsigned)(64 + 16*g)) ^ pkey));
      s8v pa0 = pa0u.s, pa1 = pa1u.s;
      const unsigned vkey = ((unsigned)(l15 & 7)) << 4;
      #pragma unroll
      for (int t = 0; t < 8; ++t) {
        const char* vrow = VT + (16*t + l15)*128;
        union { uint4 u; s8v s; } b0, b1;
        b0.u = *(const uint4*)(vrow + (((unsigned)(16*g)) ^ vkey));
        b1.u = *(const uint4*)(vrow + (((unsigned)(64 + 16*g)) ^ vkey));
        oacc[t] = __builtin_amdgcn_mfma_f32_16x16x32_bf16(pa0, b0.s, oacc[t], 0, 0, 0);
        oacc[t] = __builtin_amdgcn_mfma_f32_16x16x32_bf16(pa1, b1.s, oacc[t], 0, 0, 0);
      }
    }
  }

  // ---- epilogue: O = oacc / l ----
  {
    float inv[4];
    #pragma unroll
    for (int r = 0; r < 4; ++r) inv[r] = 1.0f / ll[r];
    #pragma unroll
    for (int t = 0; t < 8; ++t) {
      #pragma unroll
      for (int r = 0; r < 4; ++r) {
        int row = q0 + 16*wv + 4*g + r;
        Out[hqk + (size_t)row*Dh + 16*t + l15] = oacc[t][r] * inv[r];
      }
    }
  }
}

// --------------------- sparse MFMA flash + out_cache ------------------------
__global__ __launch_bounds__(256, 2) void sparse_mfma_kernel(
    const float* __restrict__ Qm, const unsigned short* __restrict__ Khg,
    const unsigned short* __restrict__ Klg, const float* __restrict__ Vm,
    const int* __restrict__ idxList, const int* __restrict__ nSel,
    float* __restrict__ Out)
{
  extern __shared__ char smc[];
  char* KH = smc + SP_KH;
  char* KL = smc + SP_KL;
  unsigned short* VTs = (unsigned short*)(smc + SP_VT);   // [128][72]
  char* PB = smc + SP_PB;
  int* idxs = (int*)(smc + SP_IDX);

  const int id  = blockIdx.x;
  const int wid = (id & 7) * 96 + (id >> 3);
  const int h   = wid / NQB;
  const int qb  = wid % NQB;
  const int gq  = qb / 3;            // query group (192 rows)
  const int q0  = qb * BQ;

  const int tid = threadIdx.x;
  const int wv  = tid >> 6;
  const int ln  = tid & 63;
  const int g   = ln >> 4;
  const int l15 = ln & 15;

  const size_t hqk = (size_t)h * HEAD_STRIDE;

  // ---- stage Q (scaled, split hi/lo) into KH/KL; load frags ----
  {
    const float* qg = Qm + hqk + (size_t)q0 * Dh;
    #pragma unroll
    for (int it = 0; it < 8; ++it) {
      int f = tid + 256*it;
      int row = f >> 5, d0 = (f & 31) * 4;
      float4 v = *(const float4*)(qg + row*Dh + d0);
      v.x *= SCALE; v.y *= SCALE; v.z *= SCALE; v.w *= SCALE;
      unsigned short h0 = f2bf(v.x), h1 = f2bf(v.y), h2 = f2bf(v.z), h3 = f2bf(v.w);
      unsigned short o0 = f2bf(v.x - bf2f(h0)), o1 = f2bf(v.y - bf2f(h1));
      unsigned short o2 = f2bf(v.z - bf2f(h2)), o3 = f2bf(v.w - bf2f(h3));
      unsigned off = (unsigned)(row*256) + (((unsigned)(d0*2)) ^ ((unsigned)(row&7) << 4));
      uint2 hu, lu;
      hu.x = (unsigned)h0 | ((unsigned)h1<<16); hu.y = (unsigned)h2 | ((unsigned)h3<<16);
      lu.x = (unsigned)o0 | ((unsigned)o1<<16); lu.y = (unsigned)o2 | ((unsigned)o3<<16);
      *(uint2*)(KH + off) = hu;
      *(uint2*)(KL + off) = lu;
    }
  }
  __syncthreads();
  s8v qh[4], qlo[4];
  {
    const int qrow = 16*wv + l15;
    const unsigned qswz = ((unsigned)(qrow & 7)) << 4;
    #pragma unroll
    for (int k0i = 0; k0i < 4; ++k0i) {
      unsigned off = (unsigned)(qrow*256) + (((unsigned)((k0i*4 + g)*16)) ^ qswz);
      union { uint4 u; s8v s; } a, b;
      a.u = *(const uint4*)(KH + off);
      b.u = *(const uint4*)(KL + off);
      qh[k0i] = a.s; qlo[k0i] = b.s;
    }
  }

  float mo[4], ll[4];
  #pragma unroll
  for (int r = 0; r < 4; ++r) { mo[r] = -1e30f; ll[r] = 0.0f; }
  f4v oacc[8];
  #pragma unroll
  for (int t = 0; t < 8; ++t) oacc[t] = (f4v){0.f, 0.f, 0.f, 0.f};

  const unsigned kswz = ((unsigned)(l15 & 7)) << 4;

  int nsel = nSel[h*M + gq];
  if (nsel > IDXCAP) nsel = IDXCAP;
  const int* il = idxList + ((size_t)h*M + gq) * IDXCAP;
  const int nt = (nsel + TK - 1) / TK;

  for (int t = 0; t < nt; ++t) {
    const int cnt = min(TK, nsel - t*TK);
    __syncthreads();
    if (tid < 64) idxs[tid] = (tid < cnt) ? il[t*TK + tid] : 0;
    __syncthreads();

    // ---- gather-stage K (split bf16 rows) + V (fp32 -> bf16 transposed) ----
    {
      const int row = tid & 63;
      const int c = idxs[row];
      const unsigned short* khr = Khg + hqk + (size_t)c * Dh;
      const unsigned short* klr = Klg + hqk + (size_t)c * Dh;
      const unsigned swz = ((unsigned)(row & 7)) << 4;
      #pragma unroll
      for (int j = 0; j < 4; ++j) {
        int chunk = (tid >> 6) + 4*j;          // 0..15
        unsigned off = (unsigned)(row*256) + (((unsigned)(chunk*16)) ^ swz);
        *(uint4*)(KH + off) = *(const uint4*)(khr + chunk*8);
        *(uint4*)(KL + off) = *(const uint4*)(klr + chunk*8);
      }
      const float* vr = Vm + hqk + (size_t)c * Dh;
      #pragma unroll
      for (int it2 = 0; it2 < 8; ++it2) {
        int d0 = 4*((tid >> 6) + 4*it2);       // 0..124
        float4 v = *(const float4*)(vr + d0);
        VTs[(d0+0)*72 + row] = f2bf(v.x);
        VTs[(d0+1)*72 + row] = f2bf(v.y);
        VTs[(d0+2)*72 + row] = f2bf(v.z);
        VTs[(d0+3)*72 + row] = f2bf(v.w);
      }
    }
    __syncthreads();

    // ---- QK^T: 3-product split-bf16 MFMA ----
    f4v S[4];
    #pragma unroll
    for (int u = 0; u < 4; ++u) S[u] = (f4v){0.f, 0.f, 0.f, 0.f};
    #pragma unroll
    for (int k0i = 0; k0i < 4; ++k0i) {
      #pragma unroll
      for (int u = 0; u < 4; ++u) {
        unsigned off = (unsigned)(u*4096 + l15*256) + (((unsigned)((k0i*4 + g)*16)) ^ kswz);
        union { uint4 u4; s8v s; } kh_, kl_;
        kh_.u4 = *(const uint4*)(KH + off);
        kl_.u4 = *(const uint4*)(KL + off);
        S[u] = __builtin_amdgcn_mfma_f32_16x16x32_bf16(qh[k0i], kh_.s, S[u], 0, 0, 0);
        S[u] = __builtin_amdgcn_mfma_f32_16x16x32_bf16(qh[k0i], kl_.s, S[u], 0, 0, 0);
        S[u] = __builtin_amdgcn_mfma_f32_16x16x32_bf16(qlo[k0i], kh_.s, S[u], 0, 0, 0);
      }
    }
    // mask tail columns (c = 16u + l15 within tile)
    #pragma unroll
    for (int u = 0; u < 4; ++u)
      if (16*u + l15 >= cnt) S[u] = (f4v){-1e30f, -1e30f, -1e30f, -1e30f};

    // ---- online softmax ----
    float sc[4], p[4][4];
    #pragma unroll
    for (int r = 0; r < 4; ++r) {
      float v = fmaxf(fmaxf(S[0][r], S[1][r]), fmaxf(S[2][r], S[3][r]));
      v = fmaxf(v, __shfl_xor(v, 1)); v = fmaxf(v, __shfl_xor(v, 2));
      v = fmaxf(v, __shfl_xor(v, 4)); v = fmaxf(v, __shfl_xor(v, 8));
      float mn = fmaxf(mo[r], v);
      sc[r] = __expf(mo[r] - mn);
      mo[r] = mn;
    }
    #pragma unroll
    for (int r = 0; r < 4; ++r) {
      float rs = 0.f;
      #pragma unroll
      for (int u = 0; u < 4; ++u) { float pv = __expf(S[u][r] - mo[r]); p[u][r] = pv; rs += pv; }
      rs += __shfl_xor(rs, 1); rs += __shfl_xor(rs, 2);
      rs += __shfl_xor(rs, 4); rs += __shfl_xor(rs, 8);
      ll[r] = ll[r]*sc[r] + rs;
    }
    #pragma unroll
    for (int u = 0; u < 8; ++u) {
      f4v o = oacc[u];
      o[0] *= sc[0]; o[1] *= sc[1]; o[2] *= sc[2]; o[3] *= sc[3];
      oacc[u] = o;
    }
    // write P~ bf16 (swizzled)
    #pragma unroll
    for (int r = 0; r < 4; ++r) {
      int qlr = 4*g + r;
      unsigned key = ((unsigned)((qlr >> 1) & 7)) << 4;
      char* rowp = PB + wv*2048 + qlr*128;
      #pragma unroll
      for (int u = 0; u < 4; ++u) {
        unsigned off = ((unsigned)(32*u + 2*l15)) ^ key;
        *(unsigned short*)(rowp + off) = f2bf(p[u][r]);
      }
    }
    __syncthreads();

    // ---- PV: P(bf16) x V(bf16); B-frag from [d][72] transposed tile ----
    {
      const unsigned pkey = ((unsigned)((l15 >> 1) & 7)) << 4;
      const char* prow = PB + wv*2048 + l15*128;
      union { uint4 u4; s8v s; } pa0u, pa1u;
      pa0u.u4 = *(const uint4*)(prow + (((unsigned)(16*g)) ^ pkey));
      pa1u.u4 = *(const uint4*)(prow + (((unsigned)(64 + 16*g)) ^ pkey));
      s8v pa0 = pa0u.s, pa1 = pa1u.s;
      #pragma unroll
      for (int u = 0; u < 8; ++u) {
        const unsigned short* vrow = VTs + (16*u + l15)*72;
        union { uint4 u4; s8v s; } b0, b1;
        b0.u4 = *(const uint4*)(vrow + 8*g);
        b1.u4 = *(const uint4*)(vrow + 32 + 8*g);
        oacc[u] = __builtin_amdgcn_mfma_f32_16x16x32_bf16(pa0, b0.s, oacc[u], 0, 0, 0);
        oacc[u] = __builtin_amdgcn_mfma_f32_16x16x32_bf16(pa1, b1.s, oacc[u], 0, 0, 0);
      }
    }
  }

  // ---- epilogue: cache = o - spo/l ----
  {
    float inv[4];
    #pragma unroll
    for (int r = 0; r < 4; ++r) inv[r] = 1.0f / ll[r];
    #pragma unroll
    for (int t = 0; t < 8; ++t) {
      #pragma unroll
      for (int r = 0; r < 4; ++r) {
        int row = q0 + 16*wv + 4*g + r;
        size_t off = hqk + (size_t)row*Dh + 16*t + l15;
        Out[OUT_HALF + off] = Out[off] - oacc[t][r] * inv[r];
      }
    }
  }
}

// ----------------- fallback fp32 dense flash (proven R1) --------------------
__global__ __launch_bounds__(256, 1) void dense_attn_kernel(
    const float* __restrict__ Qm, const float* __restrict__ Km,
    const float* __restrict__ Vm, const float* __restrict__ PL,
    float* __restrict__ Out, float* __restrict__ csPart)
{
  extern __shared__ float sm[];
  float* qs   = sm;
  float* ks   = qs + BQ*Dh;
  float* vs   = ks + TK*Dh;
  float* pT   = vs + TK*Dh;
  float* redA = pT + TK*PT_LD;
  float* redB = redA + 16*64;
  float* redC = redB + 16*64;
  float* mrow = redC + 16*68;
  float* lrow = mrow + 64;
  float* srow = lrow + 64;
  float* wrow = srow + 64;
  float* plr  = wrow + 64;

  const int qb  = blockIdx.x;
  const int h   = blockIdx.y;
  const int q0  = qb * BQ;
  const int tid = threadIdx.x;
  const int tq  = tid & 15;
  const int tk4 = tid >> 4;
  const int swq = tq & 7;
  const int swk = tk4 & 7;

  const float* qg = Qm + (size_t)h * HEAD_STRIDE + (size_t)q0 * Dh;
  #pragma unroll
  for (int it = 0; it < 8; ++it) {
    int f = tid + 256*it;
    int row = f >> 5, d4 = f & 31;
    int e4 = d4 ^ ((row >> 2) & 7);
    float4 val = *(const float4*)(qg + row*Dh + (e4 << 2));
    val.x *= SCALE; val.y *= SCALE; val.z *= SCALE; val.w *= SCALE;
    *(float4*)(qs + row*Dh + (d4 << 2)) = val;
  }
  if (tid < 64) {
    mrow[tid] = -1e30f; lrow[tid] = 0.0f;
    plr[tid]  = PL[(size_t)h * N + q0 + tid];
  }
  float oacc[4][8];
  #pragma unroll
  for (int i = 0; i < 4; ++i)
    #pragma unroll
    for (int j = 0; j < 8; ++j) oacc[i][j] = 0.0f;

  for (int kt = 0; kt < NT; ++kt) {
    __syncthreads();
    const float* kg = Km + (size_t)h * HEAD_STRIDE + (size_t)(kt*TK) * Dh;
    const float* vg = Vm + (size_t)h * HEAD_STRIDE + (size_t)(kt*TK) * Dh;
    #pragma unroll
    for (int it = 0; it < 8; ++it) {
      int f = tid + 256*it;
      int row = f >> 5, d4 = f & 31;
      int e4 = d4 ^ ((row >> 2) & 7);
      *(float4*)(ks + row*Dh + (d4 << 2)) = *(const float4*)(kg + row*Dh + (e4 << 2));
      *(float4*)(vs + row*Dh + (d4 << 2)) = *(const float4*)(vg + row*Dh + (d4 << 2));
    }
    __syncthreads();

    float acc[4][4];
    #pragma unroll
    for (int i = 0; i < 4; ++i)
      #pragma unroll
      for (int j = 0; j < 4; ++j) acc[i][j] = 0.0f;
    for (int d4 = 0; d4 < 32; ++d4) {
      const int qo = ((d4 ^ swq) << 2);
      const int ko = ((d4 ^ swk) << 2);
      float4 qv[4], kv[4];
      #pragma unroll
      for (int i = 0; i < 4; ++i) qv[i] = *(const float4*)(qs + (4*tq + i)*Dh + qo);
      #pragma unroll
      for (int j = 0; j < 4; ++j) kv[j] = *(const float4*)(ks + (4*tk4 + j)*Dh + ko);
      #pragma unroll
      for (int i = 0; i < 4; ++i)
        #pragma unroll
        for (int j = 0; j < 4; ++j)
          acc[i][j] += qv[i].x*kv[j].x + qv[i].y*kv[j].y + qv[i].z*kv[j].z + qv[i].w*kv[j].w;
    }
    #pragma unroll
    for (int i = 0; i < 4; ++i) {
      float rm = fmaxf(fmaxf(acc[i][0], acc[i][1]), fmaxf(acc[i][2], acc[i][3]));
      redA[tk4*64 + 4*tq + i] = rm;
    }
    __syncthreads();
    if (tid < 64) {
      float m0 = redA[tid];
      #pragma unroll
      for (int t = 1; t < 16; ++t) m0 = fmaxf(m0, redA[t*64 + tid]);
      float mo_ = mrow[tid];
      float mn = fmaxf(mo_, m0);
      srow[tid] = __expf(mo_ - mn);
      mrow[tid] = mn;
      wrow[tid] = __expf(mn - plr[tid]);
    }
    __syncthreads();

    float mni[4], wi[4];
    #pragma unroll
    for (int i = 0; i < 4; ++i) { mni[i] = mrow[4*tq + i]; wi[i] = wrow[4*tq + i]; }
    float rs[4] = {0.f,0.f,0.f,0.f};
    float cl[4] = {0.f,0.f,0.f,0.f};
    float pv_[4][4];
    #pragma unroll
    for (int i = 0; i < 4; ++i)
      #pragma unroll
      for (int j = 0; j < 4; ++j) {
        float pv = __expf(acc[i][j] - mni[i]);
        pv_[i][j] = pv; rs[i] += pv; cl[j] += pv * wi[i];
      }
    #pragma unroll
    for (int j = 0; j < 4; ++j) {
      float4 pj; pj.x = pv_[0][j]; pj.y = pv_[1][j]; pj.z = pv_[2][j]; pj.w = pv_[3][j];
      *(float4*)(pT + (4*tk4 + j)*PT_LD + 4*tq) = pj;
    }
    #pragma unroll
    for (int i = 0; i < 4; ++i) redB[tk4*64 + 4*tq + i] = rs[i];
    #pragma unroll
    for (int j = 0; j < 4; ++j) redC[tq*68 + 4*tk4 + j] = cl[j];
    __syncthreads();
    if (tid < 64) {
      float s0 = redB[tid];
      #pragma unroll
      for (int t = 1; t < 16; ++t) s0 += redB[t*64 + tid];
      lrow[tid] = lrow[tid]*srow[tid] + s0;
      float c0 = redC[tid];
      #pragma unroll
      for (int t = 1; t < 16; ++t) c0 += redC[t*68 + tid];
      csPart[((size_t)h*NQB + qb)*N + kt*TK + tid] = c0;
    }

    float scl[4];
    #pragma unroll
    for (int i = 0; i < 4; ++i) scl[i] = srow[4*tq + i];
    #pragma unroll
    for (int i = 0; i < 4; ++i)
      #pragma unroll
      for (int j = 0; j < 8; ++j) oacc[i][j] *= scl[i];
    for (int kk = 0; kk < TK; ++kk) {
      float4 p4 = *(const float4*)(pT + kk*PT_LD + 4*tq);
      float4 va = *(const float4*)(vs + kk*Dh + (tk4 << 3));
      float4 vb = *(const float4*)(vs + kk*Dh + (tk4 << 3) + 4);
      float p_[4]; p_[0]=p4.x; p_[1]=p4.y; p_[2]=p4.z; p_[3]=p4.w;
      float v_[8]; v_[0]=va.x; v_[1]=va.y; v_[2]=va.z; v_[3]=va.w;
                   v_[4]=vb.x; v_[5]=vb.y; v_[6]=vb.z; v_[7]=vb.w;
      #pragma unroll
      for (int i = 0; i < 4; ++i)
        #pragma unroll
        for (int j = 0; j < 8; ++j) oacc[i][j] += p_[i] * v_[j];
    }
  }

  __syncthreads();
  #pragma unroll
  for (int i = 0; i < 4; ++i) {
    float inv = 1.0f / lrow[4*tq + i];
    size_t off = (size_t)h * HEAD_STRIDE + (size_t)(q0 + 4*tq + i) * Dh + (tk4 << 3);
    float4 a, b;
    a.x = oacc[i][0]*inv; a.y = oacc[i][1]*inv; a.z = oacc[i][2]*inv; a.w = oacc[i][3]*inv;
    b.x = oacc[i][4]*inv; b.y = oacc[i][5]*inv; b.z = oacc[i][6]*inv; b.w = oacc[i][7]*inv;
    *(float4*)(Out + off)     = a;
    *(float4*)(Out + off + 4) = b;
  }
}

// --------- selection: radix top-k + exact fp32 window + random mask ---------
__global__ __launch_bounds__(256) void select_kernel(
    const float* __restrict__ csPart, const int* __restrict__ topkPtr,
    const float* __restrict__ Qm, const float* __restrict__ Km,
    const float* __restrict__ PL,
    int* __restrict__ idxList, int* __restrict__ nSel)
{
  __shared__ uint32_t ubits[N];
  __shared__ int hist[256];
  __shared__ int cnt1[256], base1[256];
  __shared__ int sh_digit, sh_kk, sh_total, sh_A, sh_C;
  __shared__ float kcol[128];
  __shared__ float exacc[4];
  __shared__ int candIdx[CAND_MAX];
  __shared__ float candEx[CAND_MAX];
  __shared__ unsigned char candSel[CAND_MAX];
  __shared__ unsigned char selmap[N];

  const int bh = blockIdx.x;
  const int h = bh >> 4, g = bh & 15;
  const int tid = threadIdx.x;

  const float* p0 = csPart + ((size_t)h*NQB + 3*g) * N;
  for (int c = tid; c < N; c += 256) {
    float v = p0[c] + p0[N + c] + p0[2*(size_t)N + c];
    ubits[c] = __float_as_uint(v);
    selmap[c] = 0;
  }
  __syncthreads();

  const int K = topkPtr[0];
  uint32_t prefix = 0; int kk = K;
  for (int pass = 0; pass < 4; ++pass) {
    const int shift = 24 - 8*pass;
    const uint32_t hm = (pass == 0) ? 0u : (0xFFFFFFFFu << (shift + 8));
    hist[tid] = 0;
    __syncthreads();
    for (int c = tid; c < N; c += 256) {
      uint32_t b = ubits[c];
      if ((b & hm) == (prefix & hm)) atomicAdd(&hist[(b >> shift) & 255], 1);
    }
    __syncthreads();
    if (tid == 0) {
      int cum = 0, d = 255;
      for (; d > 0; --d) { int hc = hist[d]; if (cum + hc >= kk) break; cum += hc; }
      sh_digit = d; sh_kk = kk - cum;
    }
    __syncthreads();
    prefix |= ((uint32_t)sh_digit) << shift;
    kk = sh_kk;
    __syncthreads();
  }
  const float thrv = __uint_as_float(prefix);   // coarse K-th largest (cs > 0)
  const float hiv  = thrv * 1.001f;
  const float lov  = thrv * 0.999f;

  // classify: definite-in (A) vs candidates (window)
  if (tid == 0) { sh_A = 0; sh_C = 0; }
  __syncthreads();
  const int CH = N / 256;
  const int c0 = tid * CH;
  int myIn = 0;
  for (int j = 0; j < CH; ++j) {
    float v = __uint_as_float(ubits[c0 + j]);
    if (v > hiv) myIn++;
    else if (v >= lov) {
      int slot = atomicAdd(&sh_C, 1);
      if (slot < CAND_MAX) candIdx[slot] = c0 + j;
    }
  }
  atomicAdd(&sh_A, myIn);
  __syncthreads();
  const int A = sh_A;
  const int C = min(sh_C, CAND_MAX);
  int need = K - A;
  if (need < 0) need = 0;
  if (need > C) need = C;

  // exact fp32 recompute of candidate colsums
  const float* Qg = Qm + (size_t)h*HEAD_STRIDE + (size_t)(g*192)*Dh;
  const float* Kg = Km + (size_t)h*HEAD_STRIDE;
  const float  plq = (tid < 192) ? PL[(size_t)h*N + g*192 + tid] : 0.f;
  for (int ci = 0; ci < C; ++ci) {
    int c = candIdx[ci];
    if (tid < 128) kcol[tid] = Kg[(size_t)c*Dh + tid];
    __syncthreads();
    float e = 0.f;
    if (tid < 192) {
      const float* qr = Qg + (size_t)tid*Dh;
      float acc = 0.f;
      #pragma unroll
      for (int d4 = 0; d4 < 32; ++d4) {
        float4 qv = *(const float4*)(qr + d4*4);
        acc += qv.x*kcol[d4*4] + qv.y*kcol[d4*4+1] + qv.z*kcol[d4*4+2] + qv.w*kcol[d4*4+3];
      }
      e = expf(acc*SCALE - plq);
    }
    #pragma unroll
    for (int s = 1; s < 64; s <<= 1) e += __shfl_xor(e, s);
    if ((tid & 63) == 0) exacc[tid >> 6] = e;
    __syncthreads();
    if (tid == 0) candEx[ci] = (exacc[0] + exacc[1]) + (exacc[2] + exacc[3]);
    __syncthreads();
  }

  // rank candidates by (exact desc, idx asc); select first `need`
  if (tid < C) {
    float ei = candEx[tid]; int ii = candIdx[tid];
    int rank = 0;
    for (int j = 0; j < C; ++j) {
      float ej = candEx[j];
      if (ej > ei || (ej == ei && candIdx[j] < ii)) ++rank;
    }
    candSel[tid] = (rank < need) ? 1 : 0;
  }
  __syncthreads();
  if (tid < C && candSel[tid]) selmap[candIdx[tid]] = 1;
  __syncthreads();

  // final flags: definite-in | selected candidate | random
  bool fl[12]; int selc = 0;
  for (int j = 0; j < CH; ++j) {
    int c = c0 + j;
    float v = __uint_as_float(ubits[c]);
    bool s = (v > hiv) || (selmap[c] != 0);
    if (!s) s = jax_rand_zero((uint32_t)bh * (uint32_t)N + (uint32_t)c);
    fl[j] = s; selc += s ? 1 : 0;
  }
  cnt1[tid] = selc;
  __syncthreads();
  if (tid == 0) { int run = 0; for (int t = 0; t < 256; ++t) { base1[t] = run; run += cnt1[t]; } sh_total = run; }
  __syncthreads();
  int w = base1[tid];
  int* il = idxList + (size_t)bh * IDXCAP;
  for (int j = 0; j < CH; ++j) if (fl[j]) { if (w < IDXCAP) il[w] = c0 + j; ++w; }
  if (tid == 0) nSel[bh] = (sh_total < IDXCAP) ? sh_total : IDXCAP;
}

// ------------------ fallback fp32 sparse flash + out_cache ------------------
__global__ __launch_bounds__(256, 1) void sparse_attn_kernel(
    const float* __restrict__ Qm, const float* __restrict__ Km,
    const float* __restrict__ Vm, const int* __restrict__ idxList,
    const int* __restrict__ nSel, float* __restrict__ Out)
{
  extern __shared__ float sm[];
  float* qs   = sm;
  float* ks   = qs + BQ*Dh;
  float* vs   = ks + TK*Dh;
  float* pT   = vs + TK*Dh;
  float* redA = pT + TK*PT_LD;
  float* redB = redA + 16*64;
  float* mrow = redB + 16*64;
  float* lrow = mrow + 64;
  float* srow = lrow + 64;
  int*   idxs = (int*)(srow + 64);

  const int qb  = blockIdx.x;
  const int h   = blockIdx.y;
  const int g   = qb / 3;
  const int q0  = qb * BQ;
  const int tid = threadIdx.x;
  const int tq  = tid & 15;
  const int tk4 = tid >> 4;
  const int swq = tq & 7;
  const int swk = tk4 & 7;

  int nsel = nSel[h*M + g];
  if (nsel > IDXCAP) nsel = IDXCAP;
  const int* il = idxList + ((size_t)h*M + g) * IDXCAP;

  const float* qg = Qm + (size_t)h * HEAD_STRIDE + (size_t)q0 * Dh;
  #pragma unroll
  for (int it = 0; it < 8; ++it) {
    int f = tid + 256*it;
    int row = f >> 5, d4 = f & 31;
    int e4 = d4 ^ ((row >> 2) & 7);
    float4 val = *(const float4*)(qg + row*Dh + (e4 << 2));
    val.x *= SCALE; val.y *= SCALE; val.z *= SCALE; val.w *= SCALE;
    *(float4*)(qs + row*Dh + (d4 << 2)) = val;
  }
  if (tid < 64) { mrow[tid] = -1e30f; lrow[tid] = 0.0f; }

  float oacc[4][8];
  #pragma unroll
  for (int i = 0; i < 4; ++i)
    #pragma unroll
    for (int j = 0; j < 8; ++j) oacc[i][j] = 0.0f;

  const int nt = (nsel + TK - 1) / TK;
  const float* kb = Km + (size_t)h * HEAD_STRIDE;
  const float* vb = Vm + (size_t)h * HEAD_STRIDE;

  for (int t = 0; t < nt; ++t) {
    const int cnt = min(TK, nsel - t*TK);
    __syncthreads();
    if (tid < 64) idxs[tid] = (tid < cnt) ? il[t*TK + tid] : 0;
    __syncthreads();
    #pragma unroll
    for (int it = 0; it < 8; ++it) {
      int f = tid + 256*it;
      int row = f >> 5, d4 = f & 31;
      int e4 = d4 ^ ((row >> 2) & 7);
      int c  = idxs[row];
      *(float4*)(ks + row*Dh + (d4 << 2)) = *(const float4*)(kb + (size_t)c*Dh + (e4 << 2));
      *(float4*)(vs + row*Dh + (d4 << 2)) = *(const float4*)(vb + (size_t)c*Dh + (d4 << 2));
    }
    __syncthreads();

    float acc[4][4];
    #pragma unroll
    for (int i = 0; i < 4; ++i)
      #pragma unroll
      for (int j = 0; j < 4; ++j) acc[i][j] = 0.0f;
    for (int d4 = 0; d4 < 32; ++d4) {
      const int qo = ((d4 ^ swq) << 2);
      const int ko = ((d4 ^ swk) << 2);
      float4 qv[4], kv[4];
      #pragma unroll
      for (int i = 0; i < 4; ++i) qv[i] = *(const float4*)(qs + (4*tq + i)*Dh + qo);
      #pragma unroll
      for (int j = 0; j < 4; ++j) kv[j] = *(const float4*)(ks + (4*tk4 + j)*Dh + ko);
      #pragma unroll
      for (int i = 0; i < 4; ++i)
        #pragma unroll
        for (int j = 0; j < 4; ++j)
          acc[i][j] += qv[i].x*kv[j].x + qv[i].y*kv[j].y + qv[i].z*kv[j].z + qv[i].w*kv[j].w;
    }
    #pragma unroll
    for (int j = 0; j < 4; ++j)
      if (4*tk4 + j >= cnt) { acc[0][j] = acc[1][j] = acc[2][j] = acc[3][j] = -1e30f; }

    #pragma unroll
    for (int i = 0; i < 4; ++i) {
      float rm = fmaxf(fmaxf(acc[i][0], acc[i][1]), fmaxf(acc[i][2], acc[i][3]));
      redA[tk4*64 + 4*tq + i] = rm;
    }
    __syncthreads();
    if (tid < 64) {
      float m0 = redA[tid];
      #pragma unroll
      for (int tt = 1; tt < 16; ++tt) m0 = fmaxf(m0, redA[tt*64 + tid]);
      float mo_ = mrow[tid];
      float mn = fmaxf(mo_, m0);
      srow[tid] = __expf(mo_ - mn);
      mrow[tid] = mn;
    }
    __syncthreads();

    float mni[4];
    #pragma unroll
    for (int i = 0; i < 4; ++i) mni[i] = mrow[4*tq + i];
    float rs[4] = {0.f,0.f,0.f,0.f};
    float pv_[4][4];
    #pragma unroll
    for (int i = 0; i < 4; ++i)
      #pragma unroll
      for (int j = 0; j < 4; ++j) {
        float pv = __expf(acc[i][j] - mni[i]);
        pv_[i][j] = pv; rs[i] += pv;
      }
    #pragma unroll
    for (int j = 0; j < 4; ++j) {
      float4 pj; pj.x = pv_[0][j]; pj.y = pv_[1][j]; pj.z = pv_[2][j]; pj.w = pv_[3][j];
      *(float4*)(pT + (4*tk4 + j)*PT_LD + 4*tq) = pj;
    }
    #pragma unroll
    for (int i = 0; i < 4; ++i) redB[tk4*64 + 4*tq + i] = rs[i];
    __syncthreads();
    if (tid < 64) {
      float s0 = redB[tid];
      #pragma unroll
      for (int tt = 1; tt < 16; ++tt) s0 += redB[tt*64 + tid];
      lrow[tid] = lrow[tid]*srow[tid] + s0;
    }

    float scl[4];
    #pragma unroll
    for (int i = 0; i < 4; ++i) scl[i] = srow[4*tq + i];
    #pragma unroll
    for (int i = 0; i < 4; ++i)
      #pragma unroll
      for (int j = 0; j < 8; ++j) oacc[i][j] *= scl[i];
    for (int kk = 0; kk < TK; ++kk) {
      float4 p4 = *(const float4*)(pT + kk*PT_LD + 4*tq);
      float4 va = *(const float4*)(vs + kk*Dh + (tk4 << 3));
      float4 vbv = *(const float4*)(vs + kk*Dh + (tk4 << 3) + 4);
      float p_[4]; p_[0]=p4.x; p_[1]=p4.y; p_[2]=p4.z; p_[3]=p4.w;
      float v_[8]; v_[0]=va.x; v_[1]=va.y; v_[2]=va.z; v_[3]=va.w;
                   v_[4]=vbv.x; v_[5]=vbv.y; v_[6]=vbv.z; v_[7]=vbv.w;
      #pragma unroll
      for (int i = 0; i < 4; ++i)
        #pragma unroll
        for (int j = 0; j < 8; ++j) oacc[i][j] += p_[i] * v_[j];
    }
  }

  __syncthreads();
  #pragma unroll
  for (int i = 0; i < 4; ++i) {
    float inv = 1.0f / lrow[4*tq + i];
    size_t off = (size_t)h * HEAD_STRIDE + (size_t)(q0 + 4*tq + i) * Dh + (tk4 << 3);
    float4 oa = *(const float4*)(Out + off);
    float4 ob = *(const float4*)(Out + off + 4);
    float4 ca, cb;
    ca.x = oa.x - oacc[i][0]*inv; ca.y = oa.y - oacc[i][1]*inv;
    ca.z = oa.z - oacc[i][2]*inv; ca.w = oa.w - oacc[i][3]*inv;
    cb.x = ob.x - oacc[i][4]*inv; cb.y = ob.y - oacc[i][5]*inv;
    cb.z = ob.z - oacc[i][6]*inv; cb.w = ob.w - oacc[i][7]*inv;
    *(float4*)(Out + OUT_HALF + off)     = ca;
    *(float4*)(Out + OUT_HALF + off + 4) = cb;
  }
}

// ------------------------------- launch -------------------------------------
extern "C" void kernel_launch(void* const* d_in, const int* in_sizes, int n_in,
                              void* d_out, int out_size, void* d_ws, size_t ws_size,
                              hipStream_t stream) {
  const float* q  = (const float*)d_in[0];
  const float* k  = (const float*)d_in[1];
  const float* v  = (const float*)d_in[2];
  const float* pl = (const float*)d_in[3];
  const int* topk = (const int*)d_in[4];
  float* out = (float*)d_out;
  char* ws   = (char*)d_ws;

  float* csPart = (float*)(ws + CS_B);
  int*   idxL   = (int*)(ws + IDX_B);
  int*   nSel   = (int*)(ws + NSEL_B);

  (void)hipFuncSetAttribute((const void*)dense_mfma_kernel,
      hipFuncAttributeMaxDynamicSharedMemorySize, MFMA_SM);
  (void)hipFuncSetAttribute((const void*)sparse_mfma_kernel,
      hipFuncAttributeMaxDynamicSharedMemorySize, SPMF_SM);
  (void)hipFuncSetAttribute((const void*)dense_attn_kernel,
      hipFuncAttributeMaxDynamicSharedMemorySize, DENSE_SM * 4);
  (void)hipFuncSetAttribute((const void*)sparse_attn_kernel,
      hipFuncAttributeMaxDynamicSharedMemorySize, SPARSE_SM * 4);

  if (ws_size >= NEED_B) {
    unsigned short* Kh = (unsigned short*)(ws + KH_B);
    unsigned short* Kl = (unsigned short*)(ws + KL_B);
    unsigned short* Vt = (unsigned short*)(out + OUT_HALF);  // scratch; only dense reads it
    split_bf16_kernel<<<6144, 256, 0, stream>>>(k, Kh, Kl);
    transpose_v_kernel<<<dim3(H, N/64), 256, 0, stream>>>(v, Vt);
    dense_mfma_kernel<<<768, 256, MFMA_SM, stream>>>(q, Kh, Kl, Vt, pl, out, csPart);
    select_kernel<<<dim3(H * M), 256, 0, stream>>>(csPart, topk, q, k, pl, idxL, nSel);
    sparse_mfma_kernel<<<768, 256, SPMF_SM, stream>>>(q, Kh, Kl, v, idxL, nSel, out);
  } else {
    dense_attn_kernel<<<dim3(NQB, H), 256, DENSE_SM * 4, stream>>>(q, k, v, pl, out, csPart);
    select_kernel<<<dim3(H * M), 256, 0, stream>>>(csPart, topk, q, k, pl, idxL, nSel);
    sparse_attn_kernel<<<dim3(NQB, H), 256, SPARSE_SM * 4, stream>>>(q, k, v, idxL, nSel, out);
  }
}